// Round 1
// baseline (3545.475 us; speedup 1.0000x reference)
//
#include <hip/hip_runtime.h>

// ---------------------------------------------------------------------------
// SFMCNN: 3 towers of (RBF-conv -> triangle -> crelu -> SFM-pool) x3 + FC.
// All fp32 (no fp32 MFMA on CDNA4; correctness-first VALU implementation).
//
// ws layout (floats):
//   p1  [0,        +14155776)  (3,128,64,24,24)  -- aliased by h3 later
//   p2  [14155776, +7077888)   (3,128,128,12,12)
//   S2  [21233664, +221184)    (3,128,24,24)   sum_c p1^2
//   S3  [21454848, +55296)     (3,128,12,12)   sum_c p2^2
//   wsq [21510144, +1344)      wsq1[3*64] | wsq2[3*128] | wsq3[3*256]
//   fcp [21511488, +3276800)   (256,128,100) FC partials
// total = 24,788,288 floats = ~99 MB
// ---------------------------------------------------------------------------

static const size_t OFF_P1  = 0;
static const size_t OFF_P2  = 14155776;
static const size_t OFF_S2  = 21233664;
static const size_t OFF_S3  = 21454848;
static const size_t OFF_WSQ = 21510144;
static const size_t OFF_FCP = 21511488;

// ------------------------- wsq precompute ----------------------------------
__global__ void wsq_kernel(const float* __restrict__ W1, const float* __restrict__ W2,
                           const float* __restrict__ W3, float* __restrict__ wsq) {
    int t = blockIdx.x;
    int tid = threadIdx.x;
    if (tid < 64) {
        const float* w = W1 + (size_t)(t * 64 + tid) * 25;
        float s = 0.f;
        for (int k = 0; k < 25; ++k) s += w[k] * w[k];
        wsq[t * 64 + tid] = s;
    } else if (tid < 192) {
        int c = tid - 64;
        const float* w = W2 + (size_t)(t * 128 + c) * 576;
        float s = 0.f;
        for (int k = 0; k < 576; ++k) s += w[k] * w[k];
        wsq[192 + t * 128 + c] = s;
    } else {
        int c = tid - 192;
        const float* w = W3 + (size_t)(t * 256 + c) * 1152;
        float s = 0.f;
        for (int k = 0; k < 1152; ++k) s += w[k] * w[k];
        wsq[576 + t * 256 + c] = s;
    }
}

// ------------------------- conv1 + pool ------------------------------------
// grid (384, 4), block 256. One (t,b) image per blockIdx.x; 16 channels per y.
__global__ __launch_bounds__(256) void conv1_kernel(
        const float* __restrict__ x, const float* __restrict__ W1,
        const float* __restrict__ triw, const float* __restrict__ crb,
        const float* __restrict__ alp, const float* __restrict__ wsqb,
        float* __restrict__ p1) {
    __shared__ float simg[52 * 52];   // zero-padded input (pad=2)
    __shared__ float srs[52 * 48];    // horizontal 5-window sums of x^2
    __shared__ float sxq[48 * 48];    // full 5x5 window sums (= xsq per conv pt)
    __shared__ float sw[16 * 25];
    __shared__ float swq[16];

    int tb = blockIdx.x;
    int b = tb / 3, t = tb % 3;
    int c0 = blockIdx.y * 16;
    int tid = threadIdx.x;
    const float* xim = x + (size_t)(b * 3 + t) * 2304;

    for (int idx = tid; idx < 52 * 52; idx += 256) {
        int y = idx / 52 - 2, xx = idx % 52 - 2;
        simg[idx] = (y >= 0 && y < 48 && xx >= 0 && xx < 48) ? xim[y * 48 + xx] : 0.f;
    }
    for (int idx = tid; idx < 16 * 25; idx += 256)
        sw[idx] = W1[(size_t)(t * 64 + c0 + idx / 25) * 25 + idx % 25];
    if (tid < 16) swq[tid] = wsqb[t * 64 + c0 + tid];
    __syncthreads();

    for (int idx = tid; idx < 52 * 48; idx += 256) {
        int i = idx / 48, ox = idx % 48;
        const float* r = &simg[i * 52 + ox];
        float s = 0.f;
#pragma unroll
        for (int j = 0; j < 5; ++j) s += r[j] * r[j];
        srs[idx] = s;
    }
    __syncthreads();
    for (int idx = tid; idx < 48 * 48; idx += 256) {
        int oy = idx / 48, ox = idx % 48;
        float s = 0.f;
#pragma unroll
        for (int i = 0; i < 5; ++i) s += srs[(oy + i) * 48 + ox];
        sxq[idx] = s;
    }
    __syncthreads();

    float tw = triw[t * 3 + 0], itw = 1.f / tw;
    float cb = crb[t * 3 + 0];
    float al = alp[t * 2 + 0];
    float ap0 = al * al * al, ap1 = al * al, ap2 = al, ap3 = 1.f;

#pragma unroll 1
    for (int r = 0; r < 36; ++r) {
        int idx = r * 256 + tid;
        int c_l = idx / 576, s = idx % 576;
        int py = s / 24, px = s % 24;
        const float* wp = &sw[c_l * 25];
        float wq = swq[c_l];
        float acc = 0.f;
#pragma unroll
        for (int i = 0; i < 2; ++i)
#pragma unroll
            for (int j = 0; j < 2; ++j) {
                int oy = 2 * py + i, ox = 2 * px + j;
                float cross = 0.f;
#pragma unroll
                for (int ky = 0; ky < 5; ++ky)
#pragma unroll
                    for (int kx = 0; kx < 5; ++kx)
                        cross += simg[(oy + ky) * 52 + ox + kx] * wp[ky * 5 + kx];
                float d = sxq[oy * 48 + ox] - 2.f * cross + wq;
                d = fmaxf(d, 0.f);
                d = fminf(d, tw);
                float h = 1.f - d * itw;
                h = (h >= cb) ? h : 0.f;
                float w8 = (i == 0) ? (j == 0 ? ap0 : ap1) : (j == 0 ? ap2 : ap3);
                acc += h * w8;
            }
        p1[((size_t)(t * 128 + b) * 64 + c0 + c_l) * 576 + s] = acc * 0.25f;
    }
}

// ------------------------- channel sum-of-squares --------------------------
__global__ void s2_kernel(const float* __restrict__ p1, float* __restrict__ S2) {
    int tb = blockIdx.x;
    int b = tb / 3, t = tb % 3;
    int tid = threadIdx.x;
    const float* base = p1 + (size_t)(t * 128 + b) * 64 * 576;
    for (int s = tid; s < 576; s += 256) {
        float acc = 0.f;
        for (int c = 0; c < 64; ++c) {
            float v = base[(size_t)c * 576 + s];
            acc += v * v;
        }
        S2[(size_t)(t * 128 + b) * 576 + s] = acc;
    }
}

__global__ void s3_kernel(const float* __restrict__ p2, float* __restrict__ S3) {
    int tb = blockIdx.x;
    int b = tb / 3, t = tb % 3;
    int tid = threadIdx.x;
    const float* base = p2 + (size_t)(t * 128 + b) * 128 * 144;
    for (int s = tid; s < 144; s += 256) {
        float acc = 0.f;
        for (int c = 0; c < 128; ++c) {
            float v = base[(size_t)c * 144 + s];
            acc += v * v;
        }
        S3[(size_t)(t * 128 + b) * 144 + s] = acc;
    }
}

// ------------------------- conv2 + pool ------------------------------------
// grid (384, 8), block 576 = 16 co x 36 spatial threads.
// Thread: 2x2 pooled outputs = 4x4 pre-pool conv points (16 cross accs).
// Input staged in 8-ci chunks, rows padded to 28 floats (16B aligned).
__global__ __launch_bounds__(576, 5) void conv2_kernel(
        const float* __restrict__ p1, const float* __restrict__ W2,
        const float* __restrict__ S2, const float* __restrict__ triw,
        const float* __restrict__ crb, const float* __restrict__ alp,
        const float* __restrict__ wsqb, float* __restrict__ p2) {
    __shared__ float sIn[8 * 26 * 28];   // [ci][26 rows][28 stride] padded
    __shared__ float sW[16 * 72];        // [co][8ci*9]
    __shared__ float sS[26 * 26];        // padded S2

    int tb = blockIdx.x;
    int b = tb / 3, t = tb % 3;
    int co0 = blockIdx.y * 16;
    int tid = threadIdx.x;
    int co_l = tid / 36, sp = tid % 36;
    int pby = (sp / 6) * 2, pbx = (sp % 6) * 2;   // pooled tile base
    int row0 = 2 * pby, col0 = 2 * pbx;           // padded LDS base

    const float* s2base = S2 + (size_t)(t * 128 + b) * 576;
    for (int idx = tid; idx < 676; idx += 576) {
        int y = idx / 26 - 1, xx = idx % 26 - 1;
        sS[idx] = (y >= 0 && y < 24 && xx >= 0 && xx < 24) ? s2base[y * 24 + xx] : 0.f;
    }

    float acc[16];
#pragma unroll
    for (int i = 0; i < 16; ++i) acc[i] = 0.f;

    const float* inbase = p1 + (size_t)(t * 128 + b) * 64 * 576;
    const float* wbase = W2 + (size_t)(t * 128 + co0) * 576;

    for (int cc = 0; cc < 8; ++cc) {
        __syncthreads();
        for (int idx = tid; idx < 8 * 676; idx += 576) {
            int ci_l = idx / 676, r = idx % 676;
            int y = r / 26 - 1, xx = r % 26 - 1;
            sIn[ci_l * 728 + (r / 26) * 28 + (r % 26)] =
                (y >= 0 && y < 24 && xx >= 0 && xx < 24)
                    ? inbase[(size_t)(cc * 8 + ci_l) * 576 + y * 24 + xx] : 0.f;
        }
        for (int idx = tid; idx < 16 * 72; idx += 576) {
            int c2 = idx / 72, kk = idx % 72;
            sW[idx] = wbase[(size_t)c2 * 576 + cc * 72 + kk];
        }
        __syncthreads();
#pragma unroll 2
        for (int ci_l = 0; ci_l < 8; ++ci_l) {
            const float* src = &sIn[ci_l * 728 + row0 * 28 + col0];
            float xv[36];
#pragma unroll
            for (int r = 0; r < 6; ++r)
#pragma unroll
                for (int c = 0; c < 6; ++c)
                    xv[r * 6 + c] = src[r * 28 + c];
            const float* wp = &sW[co_l * 72 + ci_l * 9];
#pragma unroll
            for (int ky = 0; ky < 3; ++ky)
#pragma unroll
                for (int kx = 0; kx < 3; ++kx) {
                    float wv = wp[ky * 3 + kx];
#pragma unroll
                    for (int u = 0; u < 4; ++u)
#pragma unroll
                        for (int v = 0; v < 4; ++v)
                            acc[u * 4 + v] += xv[(u + ky) * 6 + v + kx] * wv;
                }
        }
    }

    float wq = wsqb[192 + t * 128 + co0 + co_l];
    float tw = triw[t * 3 + 1], itw = 1.f / tw;
    float cb = crb[t * 3 + 1];
    float al = alp[t * 2 + 1];
    float ap[4] = {al * al * al, al * al, al, 1.f};
    float* outb = p2 + ((size_t)(t * 128 + b) * 128 + co0 + co_l) * 144;

#pragma unroll
    for (int i2 = 0; i2 < 2; ++i2)
#pragma unroll
        for (int j2 = 0; j2 < 2; ++j2) {
            float psum = 0.f;
#pragma unroll
            for (int du = 0; du < 2; ++du)
#pragma unroll
                for (int dv = 0; dv < 2; ++dv) {
                    int u = i2 * 2 + du, v = j2 * 2 + dv;
                    int oy = row0 + u, ox = col0 + v;
                    float xsq = 0.f;
#pragma unroll
                    for (int ky = 0; ky < 3; ++ky)
#pragma unroll
                        for (int kx = 0; kx < 3; ++kx)
                            xsq += sS[(oy + ky) * 26 + ox + kx];
                    float d = xsq - 2.f * acc[u * 4 + v] + wq;
                    d = fmaxf(d, 0.f);
                    d = fminf(d, tw);
                    float h = 1.f - d * itw;
                    h = (h >= cb) ? h : 0.f;
                    psum += h * ap[du * 2 + dv];
                }
            outb[(pby + i2) * 12 + pbx + j2] = psum * 0.25f;
        }
}

// ------------------------- conv3 (no pool) ---------------------------------
// grid (384, 4), block 576 = 64 co x 9 spatial threads (4x4 points each).
__global__ __launch_bounds__(576, 5) void conv3_kernel(
        const float* __restrict__ p2, const float* __restrict__ W3,
        const float* __restrict__ S3, const float* __restrict__ triw,
        const float* __restrict__ crb, const float* __restrict__ wsqb,
        float* __restrict__ h3) {
    __shared__ float sIn[8 * 14 * 16];   // [ci][14 rows][16 stride] padded
    __shared__ float sW[64 * 72];
    __shared__ float sS[14 * 14];

    int tb = blockIdx.x;
    int b = tb / 3, t = tb % 3;
    int co0 = blockIdx.y * 64;
    int tid = threadIdx.x;
    int co_l = tid / 9, sp = tid % 9;
    int by = (sp / 3) * 4, bx = (sp % 3) * 4;

    const float* s3base = S3 + (size_t)(t * 128 + b) * 144;
    for (int idx = tid; idx < 196; idx += 576) {
        int y = idx / 14 - 1, xx = idx % 14 - 1;
        sS[idx] = (y >= 0 && y < 12 && xx >= 0 && xx < 12) ? s3base[y * 12 + xx] : 0.f;
    }

    float acc[16];
#pragma unroll
    for (int i = 0; i < 16; ++i) acc[i] = 0.f;

    const float* inbase = p2 + (size_t)(t * 128 + b) * 128 * 144;
    const float* wbase = W3 + (size_t)(t * 256 + co0) * 1152;

    for (int cc = 0; cc < 16; ++cc) {
        __syncthreads();
        for (int idx = tid; idx < 8 * 196; idx += 576) {
            int ci_l = idx / 196, r = idx % 196;
            int y = r / 14 - 1, xx = r % 14 - 1;
            sIn[ci_l * 224 + (r / 14) * 16 + (r % 14)] =
                (y >= 0 && y < 12 && xx >= 0 && xx < 12)
                    ? inbase[(size_t)(cc * 8 + ci_l) * 144 + y * 12 + xx] : 0.f;
        }
        for (int idx = tid; idx < 64 * 72; idx += 576) {
            int c2 = idx / 72, kk = idx % 72;
            sW[idx] = wbase[(size_t)c2 * 1152 + cc * 72 + kk];
        }
        __syncthreads();
#pragma unroll 2
        for (int ci_l = 0; ci_l < 8; ++ci_l) {
            const float* src = &sIn[ci_l * 224 + by * 16 + bx];
            float xv[36];
#pragma unroll
            for (int r = 0; r < 6; ++r)
#pragma unroll
                for (int c = 0; c < 6; ++c)
                    xv[r * 6 + c] = src[r * 16 + c];
            const float* wp = &sW[co_l * 72 + ci_l * 9];
#pragma unroll
            for (int ky = 0; ky < 3; ++ky)
#pragma unroll
                for (int kx = 0; kx < 3; ++kx) {
                    float wv = wp[ky * 3 + kx];
#pragma unroll
                    for (int u = 0; u < 4; ++u)
#pragma unroll
                        for (int v = 0; v < 4; ++v)
                            acc[u * 4 + v] += xv[(u + ky) * 6 + v + kx] * wv;
                }
        }
    }

    float wq = wsqb[576 + t * 256 + co0 + co_l];
    float tw = triw[t * 3 + 2], itw = 1.f / tw;
    float cb = crb[t * 3 + 2];
    float* outb = h3 + (size_t)b * 110592 + (size_t)t * 36864 + (size_t)(co0 + co_l) * 144;

#pragma unroll
    for (int u = 0; u < 4; ++u)
#pragma unroll
        for (int v = 0; v < 4; ++v) {
            int oy = by + u, ox = bx + v;
            float xsq = 0.f;
#pragma unroll
            for (int ky = 0; ky < 3; ++ky)
#pragma unroll
                for (int kx = 0; kx < 3; ++kx)
                    xsq += sS[(oy + ky) * 14 + ox + kx];
            float d = xsq - 2.f * acc[u * 4 + v] + wq;
            d = fmaxf(d, 0.f);
            d = fminf(d, tw);
            float h = 1.f - d * itw;
            h = (h >= cb) ? h : 0.f;
            outb[oy * 12 + ox] = h;
        }
}

// ------------------------- FC: K-split partials + reduce -------------------
// grid 256 (one 432-wide F-slab each), block 256 = 32 b-groups x 8 o-groups.
__global__ __launch_bounds__(256) void fc_partial_kernel(
        const float* __restrict__ h3, const float* __restrict__ fcw,
        float* __restrict__ part) {
    __shared__ float sH[128 * 49];    // +1 pad breaks the 192-stride conflict
    __shared__ float sWf[104 * 48];   // 4 zero rows so io-loop needs no guard

    int kb = blockIdx.x;
    int tid = threadIdx.x;
    int f0 = kb * 432;
    int bg = tid & 31, og = tid >> 5;
    int b0 = bg * 4, o0 = og * 13;

    float acc[4][13];
#pragma unroll
    for (int i = 0; i < 4; ++i)
#pragma unroll
        for (int j = 0; j < 13; ++j) acc[i][j] = 0.f;

    for (int fc = 0; fc < 9; ++fc) {
        int fbase = f0 + fc * 48;
        __syncthreads();
        for (int idx = tid; idx < 128 * 48; idx += 256) {
            int bb = idx / 48, ff = idx % 48;
            sH[bb * 49 + ff] = h3[(size_t)bb * 110592 + fbase + ff];
        }
        for (int idx = tid; idx < 104 * 48; idx += 256) {
            int oo = idx / 48, ff = idx % 48;
            sWf[idx] = (oo < 100) ? fcw[(size_t)oo * 110592 + fbase + ff] : 0.f;
        }
        __syncthreads();
#pragma unroll 4
        for (int ff = 0; ff < 48; ++ff) {
            float hv[4];
#pragma unroll
            for (int ib = 0; ib < 4; ++ib) hv[ib] = sH[(b0 + ib) * 49 + ff];
#pragma unroll
            for (int io = 0; io < 13; ++io) {
                float wv = sWf[(o0 + io) * 48 + ff];
#pragma unroll
                for (int ib = 0; ib < 4; ++ib) acc[ib][io] += hv[ib] * wv;
            }
        }
    }

    int on = (og == 7) ? 9 : 13;
    float* pb = part + (size_t)kb * 12800;
    for (int ib = 0; ib < 4; ++ib)
        for (int io = 0; io < on; ++io)
            pb[(b0 + ib) * 100 + o0 + io] = acc[ib][io];
}

__global__ void fc_reduce_kernel(const float* __restrict__ part,
                                 const float* __restrict__ fcb,
                                 float* __restrict__ out) {
    int gid = blockIdx.x * 256 + threadIdx.x;
    if (gid >= 12800) return;
    int o = gid % 100;
    float s = fcb[o];
    for (int kb = 0; kb < 256; ++kb) s += part[(size_t)kb * 12800 + gid];
    out[gid] = s;
}

// ---------------------------------------------------------------------------
extern "C" void kernel_launch(void* const* d_in, const int* in_sizes, int n_in,
                              void* d_out, int out_size, void* d_ws, size_t ws_size,
                              hipStream_t stream) {
    const float* x    = (const float*)d_in[0];
    const float* W1   = (const float*)d_in[1];
    const float* W2   = (const float*)d_in[2];
    const float* W3   = (const float*)d_in[3];
    const float* triw = (const float*)d_in[4];
    const float* crb  = (const float*)d_in[5];
    const float* alp  = (const float*)d_in[6];
    const float* fcw  = (const float*)d_in[7];
    const float* fcb  = (const float*)d_in[8];
    float* out = (float*)d_out;
    float* ws  = (float*)d_ws;

    float* p1  = ws + OFF_P1;
    float* p2  = ws + OFF_P2;
    float* S2  = ws + OFF_S2;
    float* S3  = ws + OFF_S3;
    float* wsq = ws + OFF_WSQ;
    float* fcp = ws + OFF_FCP;
    float* h3  = p1;   // p1 is dead once conv2 finishes; alias for h3

    wsq_kernel<<<dim3(3), dim3(448), 0, stream>>>(W1, W2, W3, wsq);
    conv1_kernel<<<dim3(384, 4), dim3(256), 0, stream>>>(x, W1, triw, crb, alp, wsq, p1);
    s2_kernel<<<dim3(384), dim3(256), 0, stream>>>(p1, S2);
    conv2_kernel<<<dim3(384, 8), dim3(576), 0, stream>>>(p1, W2, S2, triw, crb, alp, wsq, p2);
    s3_kernel<<<dim3(384), dim3(256), 0, stream>>>(p2, S3);
    conv3_kernel<<<dim3(384, 4), dim3(576), 0, stream>>>(p2, W3, S3, triw, crb, wsq, h3);
    fc_partial_kernel<<<dim3(256), dim3(256), 0, stream>>>(h3, fcw, fcp);
    fc_reduce_kernel<<<dim3(50), dim3(256), 0, stream>>>(fcp, fcb, out);
}

// Round 2
// 669.960 us; speedup vs baseline: 5.2921x; 5.2921x over previous
//
#include <hip/hip_runtime.h>

// ---------------------------------------------------------------------------
// SFMCNN via bf16 MFMA: RBF-conv = xsq - 2*cross + wsq; cross via im2col GEMM
// on the matrix cores (16x16x32 bf16), xsq/wsq in fp32 from the SAME
// bf16-rounded values (consistent quantization). Triangle/crelu/pool fused.
//
// ws layout (float offsets):
//   R1 [0, 14155776):      p1cl bf16 (3,128,26,26,64) halo-baked  -> later h3 fp32 (128,110592)
//   p2cl [14155776, +4816896): bf16 (3,128,14,14,128) halo-baked
//   S2   [18972672, +221184)   fp32 per-pixel sum_ci p1^2
//   S3   [19193856, +55296)
//   wsq  [19249152, +1344)     wsq1 | wsq2(bf16-rounded) | wsq3(bf16-rounded)
//   W2s  [19250496, +110592)   bf16 (3,9,128co,64ci)
//   W3s  [19361088, +442368)   bf16 (3,9,256co,128ci)
//   fcp  [19803456, +3276800)
// total 23,080,256 floats = 92.3 MB (round-1 used 99.2 MB => fits)
// ---------------------------------------------------------------------------

static const size_t OFF_P2CL = 14155776;
static const size_t OFF_S2   = 18972672;
static const size_t OFF_S3   = 19193856;
static const size_t OFF_WSQ  = 19249152;
static const size_t OFF_W2S  = 19250496;
static const size_t OFF_W3S  = 19361088;
static const size_t OFF_FCP  = 19803456;

typedef short bf16x8 __attribute__((ext_vector_type(8)));
typedef float f32x4 __attribute__((ext_vector_type(4)));

__device__ __forceinline__ unsigned short f2bf(float f) {
    union { float f; unsigned u; } v; v.f = f;
    unsigned r = (v.u + 0x7FFFu + ((v.u >> 16) & 1u)) >> 16;
    return (unsigned short)r;
}
__device__ __forceinline__ float bf2f(unsigned short h) {
    union { unsigned u; float f; } v; v.u = ((unsigned)h) << 16;
    return v.f;
}
__device__ __forceinline__ float sq8(uint4 u) {
    float s = 0.f;
    const unsigned* p = (const unsigned*)&u;
#pragma unroll
    for (int j = 0; j < 4; ++j) {
        float a = bf2f((unsigned short)(p[j] & 0xFFFFu));
        float b = bf2f((unsigned short)(p[j] >> 16));
        s += a * a + b * b;
    }
    return s;
}

// ------------------------- prep: W2s/W3s bf16 reorder + wsq ----------------
__global__ __launch_bounds__(256) void prep_kernel(
        const float* __restrict__ W1, const float* __restrict__ W2,
        const float* __restrict__ W3, unsigned short* __restrict__ w2s,
        unsigned short* __restrict__ w3s, float* __restrict__ wsq) {
    int gid = blockIdx.x * 256 + threadIdx.x;   // grid 432 -> 110592 threads
#pragma unroll
    for (int k = 0; k < 2; ++k) {               // W2s: 221184 = (t,kk,co,ci)
        int e = gid * 2 + k;
        int t = e / 73728, r = e % 73728;
        int kk = r / 8192; r %= 8192;
        int co = r / 64, ci = r % 64;
        w2s[e] = f2bf(W2[(size_t)(t * 128 + co) * 576 + ci * 9 + kk]);
    }
#pragma unroll
    for (int k = 0; k < 8; ++k) {               // W3s: 884736
        int e = gid * 8 + k;
        int t = e / 294912, r = e % 294912;
        int kk = r / 32768; r %= 32768;
        int co = r / 128, ci = r % 128;
        w3s[e] = f2bf(W3[(size_t)(t * 256 + co) * 1152 + ci * 9 + kk]);
    }
    if (gid < 1344) {
        int t = gid / 448, r = gid % 448;
        if (r < 64) {
            const float* w = W1 + (size_t)(t * 64 + r) * 25; float s = 0.f;
            for (int k = 0; k < 25; ++k) s += w[k] * w[k];
            wsq[t * 64 + r] = s;
        } else if (r < 192) {
            int c = r - 64;
            const float* w = W2 + (size_t)(t * 128 + c) * 576; float s = 0.f;
            for (int k = 0; k < 576; ++k) { float v = bf2f(f2bf(w[k])); s += v * v; }
            wsq[192 + t * 128 + c] = s;
        } else {
            int c = r - 192;
            const float* w = W3 + (size_t)(t * 256 + c) * 1152; float s = 0.f;
            for (int k = 0; k < 1152; ++k) { float v = bf2f(f2bf(w[k])); s += v * v; }
            wsq[576 + t * 256 + c] = s;
        }
    }
}

// ------------------------- conv1 + pool -> p1cl bf16 channel-last ----------
// grid (384, 4), block 256. One (t,b) image per bx; 16 channels per by.
__global__ __launch_bounds__(256) void conv1_kernel(
        const float* __restrict__ x, const float* __restrict__ W1,
        const float* __restrict__ triw, const float* __restrict__ crb,
        const float* __restrict__ alp, const float* __restrict__ wsqb,
        unsigned short* __restrict__ p1u) {
    __shared__ float simg[52 * 52];
    __shared__ float sxq[48 * 48];
    __shared__ float sw[16 * 25];
    __shared__ float swq[16];
    __shared__ char spool[20736];          // srs (9984B) then htile (576*18 u16)
    float* srs = (float*)spool;
    unsigned short* htile = (unsigned short*)spool;

    int tb = blockIdx.x;
    int b = tb / 3, t = tb % 3;
    int c0 = blockIdx.y * 16;
    int tid = threadIdx.x;
    const float* xim = x + (size_t)(b * 3 + t) * 2304;

    for (int idx = tid; idx < 52 * 52; idx += 256) {
        int y = idx / 52 - 2, xx = idx % 52 - 2;
        simg[idx] = (y >= 0 && y < 48 && xx >= 0 && xx < 48) ? xim[y * 48 + xx] : 0.f;
    }
    for (int idx = tid; idx < 16 * 25; idx += 256)
        sw[idx] = W1[(size_t)(t * 64 + c0 + idx / 25) * 25 + idx % 25];
    if (tid < 16) swq[tid] = wsqb[t * 64 + c0 + tid];
    __syncthreads();

    for (int idx = tid; idx < 52 * 48; idx += 256) {
        int i = idx / 48, ox = idx % 48;
        const float* r = &simg[i * 52 + ox];
        float s = 0.f;
#pragma unroll
        for (int j = 0; j < 5; ++j) s += r[j] * r[j];
        srs[idx] = s;
    }
    __syncthreads();
    for (int idx = tid; idx < 48 * 48; idx += 256) {
        int oy = idx / 48, ox = idx % 48;
        float s = 0.f;
#pragma unroll
        for (int i = 0; i < 5; ++i) s += srs[(oy + i) * 48 + ox];
        sxq[idx] = s;
    }
    __syncthreads();   // srs dead after this; htile may reuse spool

    float tw = triw[t * 3 + 0], itw = 1.f / tw;
    float cb = crb[t * 3 + 0];
    float al = alp[t * 2 + 0];
    float ap0 = al * al * al, ap1 = al * al, ap2 = al, ap3 = 1.f;

#pragma unroll 1
    for (int r = 0; r < 36; ++r) {
        int idx = r * 256 + tid;
        int c_l = idx / 576, s = idx % 576;
        int py = s / 24, px = s % 24;
        const float* wp = &sw[c_l * 25];
        float wq = swq[c_l];
        float acc = 0.f;
#pragma unroll
        for (int i = 0; i < 2; ++i)
#pragma unroll
            for (int j = 0; j < 2; ++j) {
                int oy = 2 * py + i, ox = 2 * px + j;
                float cross = 0.f;
#pragma unroll
                for (int ky = 0; ky < 5; ++ky)
#pragma unroll
                    for (int kx = 0; kx < 5; ++kx)
                        cross += simg[(oy + ky) * 52 + ox + kx] * wp[ky * 5 + kx];
                float d = sxq[oy * 48 + ox] - 2.f * cross + wq;
                d = fminf(fmaxf(d, 0.f), tw);
                float h = 1.f - d * itw;
                h = (h >= cb) ? h : 0.f;
                float w8 = (i == 0) ? (j == 0 ? ap0 : ap1) : (j == 0 ? ap2 : ap3);
                acc += h * w8;
            }
        htile[s * 18 + c_l] = f2bf(acc * 0.25f);
    }
    __syncthreads();

    size_t imgbase = (size_t)(t * 128 + b) * 43264;   // 676*64 ushorts
    for (int s = tid; s < 576; s += 256) {
        int cell = (s / 24 + 1) * 26 + (s % 24) + 1;
        unsigned uu[8];
#pragma unroll
        for (int k = 0; k < 8; ++k)
            uu[k] = *(const unsigned*)((const char*)htile + s * 36 + k * 4);
        uint4 v0; v0.x = uu[0]; v0.y = uu[1]; v0.z = uu[2]; v0.w = uu[3];
        uint4 v1; v1.x = uu[4]; v1.y = uu[5]; v1.z = uu[6]; v1.w = uu[7];
        uint4* gp = (uint4*)(p1u + imgbase + (size_t)cell * 64 + c0);
        gp[0] = v0; gp[1] = v1;
    }
    // halo zeros (100 border cells x 16 ci)
    for (int e = tid; e < 1600; e += 256) {
        int bc = e >> 4, c_l = e & 15;
        int cell;
        if (bc < 26) cell = bc;
        else if (bc < 52) cell = 650 + (bc - 26);
        else { int r = bc - 52; cell = (1 + (r >> 1)) * 26 + ((r & 1) * 25); }
        p1u[imgbase + (size_t)cell * 64 + c0 + c_l] = 0;
    }
}

// ------------------------- S2 / S3 (from bf16-rounded values) --------------
__global__ __launch_bounds__(576) void s2_kernel(const unsigned short* __restrict__ p1u,
                                                 float* __restrict__ S2) {
    int i = blockIdx.x;                 // 0..383
    int s = threadIdx.x;                // <576
    int cell = (s / 24 + 1) * 26 + (s % 24) + 1;
    const uint4* gp = (const uint4*)(p1u + (size_t)i * 43264 + (size_t)cell * 64);
    float acc = 0.f;
#pragma unroll
    for (int k = 0; k < 8; ++k) acc += sq8(gp[k]);
    S2[(size_t)i * 576 + s] = acc;
}

__global__ __launch_bounds__(576) void s3_kernel(const unsigned short* __restrict__ p2u,
                                                 float* __restrict__ S3) {
    int g = blockIdx.x;                 // 0..95
    int tid = threadIdx.x;
    int il = tid / 144, s = tid % 144;
    int i = g * 4 + il;
    int cell = (s / 12 + 1) * 14 + (s % 12) + 1;
    const uint4* gp = (const uint4*)(p2u + ((size_t)i * 196 + cell) * 128);
    float acc = 0.f;
#pragma unroll
    for (int k = 0; k < 16; ++k) acc += sq8(gp[k]);
    S3[(size_t)i * 144 + s] = acc;
}

// ------------------------- conv2: MFMA GEMM + pool -> p2cl -----------------
// grid (384 images, 2 co-halves), block 576 = 9 waves; wave tile 64m x 64n.
// LDS (bytes): img 0..97344 (676 cells * 144B rows)  [pbuf 288*65*4 aliases]
//              sbw 97344..124992 (192 rows * 144B)
//              sS 124992 (676 f32) | sxq 127696 (576 f32) | wsqh 130000 (64 f32)
__global__ __launch_bounds__(576, 3) void conv2_kernel(
        const unsigned short* __restrict__ p1u, const unsigned short* __restrict__ w2s,
        const float* __restrict__ S2, const float* __restrict__ triw,
        const float* __restrict__ crb, const float* __restrict__ alp,
        const float* __restrict__ wsq, unsigned short* __restrict__ p2u) {
    extern __shared__ char sm[];
    float* sS   = (float*)(sm + 124992);
    float* sxq  = (float*)(sm + 127696);
    float* wsqh = (float*)(sm + 130000);
    float* pbuf = (float*)sm;

    int i = blockIdx.x;
    int t = i / 128;
    int co0 = blockIdx.y * 64;
    int tid = threadIdx.x;
    int w = tid >> 6, l = tid & 63;
    int lm = l & 15, q = l >> 4;

    {   // stage image: 676 cells x 64ci bf16 -> rows padded to 72 ushorts
        const uint4* gsrc = (const uint4*)(p1u + (size_t)i * 43264);
        for (int d = tid; d < 5408; d += 576) {
            int cell = d >> 3, c8 = d & 7;
            *(uint4*)(sm + cell * 144 + c8 * 16) = gsrc[(size_t)cell * 8 + c8];
        }
    }
    for (int e = tid; e < 676; e += 576) {
        int yy = e / 26, xx = e % 26;
        sS[e] = (yy >= 1 && yy <= 24 && xx >= 1 && xx <= 24)
                    ? S2[(size_t)i * 576 + (yy - 1) * 24 + (xx - 1)] : 0.f;
    }
    if (tid < 64) wsqh[tid] = wsq[192 + t * 128 + co0 + tid];
    __syncthreads();
    if (tid < 576) {
        int oy = tid / 24, ox = tid % 24;
        float s = 0.f;
#pragma unroll
        for (int ky = 0; ky < 3; ++ky)
#pragma unroll
            for (int kx = 0; kx < 3; ++kx) s += sS[(oy + ky) * 26 + ox + kx];
        sxq[tid] = s;
    }

    int posA[4], oyq[4], oxq[4];
#pragma unroll
    for (int mt = 0; mt < 4; ++mt) {
        int m = w * 64 + mt * 16 + lm;
        posA[mt] = (m / 24) * 26 + (m % 24);
        int sb = w * 64 + mt * 16 + q * 4;
        oyq[mt] = sb / 24; oxq[mt] = sb % 24;
    }

    f32x4 zz; zz[0] = 0.f; zz[1] = 0.f; zz[2] = 0.f; zz[3] = 0.f;
    f32x4 acc[4][4];
#pragma unroll
    for (int a = 0; a < 4; ++a)
#pragma unroll
        for (int bb = 0; bb < 4; ++bb) acc[a][bb] = zz;

    const unsigned short* w2base = w2s + (size_t)t * 9 * 128 * 64;

    for (int kg = 0; kg < 3; ++kg) {
        __syncthreads();
        for (int d = tid; d < 1536; d += 576) {     // 3 kk x 64 co x 64 ci
            int kkl = d / 512, r = d % 512;
            int n = r >> 3, c8 = r & 7;
            const uint4* g = (const uint4*)(w2base + ((size_t)(kg * 3 + kkl) * 128 + co0 + n) * 64);
            *(uint4*)(sm + 97344 + (kkl * 64 + n) * 144 + c8 * 16) = g[c8];
        }
        __syncthreads();
#pragma unroll
        for (int kkl = 0; kkl < 3; ++kkl) {
            int kk = kg * 3 + kkl;
            int kof = (kk / 3) * 26 + (kk % 3);
#pragma unroll
            for (int ks = 0; ks < 2; ++ks) {
                bf16x8 aF[4];
#pragma unroll
                for (int mt = 0; mt < 4; ++mt)
                    aF[mt] = *(const bf16x8*)(sm + (posA[mt] + kof) * 144 + ks * 64 + q * 16);
#pragma unroll
                for (int nt = 0; nt < 4; ++nt) {
                    bf16x8 bF = *(const bf16x8*)(sm + 97344 + (kkl * 64 + nt * 16 + lm) * 144 + ks * 64 + q * 16);
                    acc[0][nt] = __builtin_amdgcn_mfma_f32_16x16x32_bf16(aF[0], bF, acc[0][nt], 0, 0, 0);
                    acc[1][nt] = __builtin_amdgcn_mfma_f32_16x16x32_bf16(aF[1], bF, acc[1][nt], 0, 0, 0);
                    acc[2][nt] = __builtin_amdgcn_mfma_f32_16x16x32_bf16(aF[2], bF, acc[2][nt], 0, 0, 0);
                    acc[3][nt] = __builtin_amdgcn_mfma_f32_16x16x32_bf16(aF[3], bF, acc[3][nt], 0, 0, 0);
                }
            }
        }
    }
    __syncthreads();   // img dead -> pbuf alias

    float tw = triw[t * 3 + 1], itw = 1.f / tw, cb = crb[t * 3 + 1], al = alp[t * 2 + 1];
    float apw[4] = {al * al * al * 0.25f, al * al * 0.25f, al * 0.25f, 0.25f};
#pragma unroll
    for (int mt = 0; mt < 4; ++mt) {
        int sb = w * 64 + mt * 16 + q * 4;
        int cell = oyq[mt] * 12 + (oxq[mt] >> 1);
        int oybit = (oyq[mt] & 1) << 1;
#pragma unroll
        for (int nt = 0; nt < 4; ++nt) {
            int n = nt * 16 + lm;
            float wq = wsqh[n];
            float hw[4];
#pragma unroll
            for (int r = 0; r < 4; ++r) {
                float d = sxq[sb + r] - 2.f * acc[mt][nt][r] + wq;
                d = fminf(fmaxf(d, 0.f), tw);
                float h = 1.f - d * itw;
                h = (h >= cb) ? h : 0.f;
                hw[r] = h * apw[oybit | (r & 1)];
            }
            pbuf[cell * 65 + n] = hw[0] + hw[1];
            pbuf[(cell + 1) * 65 + n] = hw[2] + hw[3];
        }
    }
    __syncthreads();
    // vertical pool + p2cl write (halo-baked layout)
    for (int e = tid; e < 9216; e += 576) {
        int co_l = e & 63, pp = e >> 6;
        int py = pp / 12, px = pp % 12;
        float v = pbuf[((2 * py) * 12 + px) * 65 + co_l] +
                  pbuf[((2 * py + 1) * 12 + px) * 65 + co_l];
        p2u[((size_t)i * 196 + (py + 1) * 14 + px + 1) * 128 + co0 + co_l] = f2bf(v);
    }
    for (int e = tid; e < 3328; e += 576) {      // 52 border cells x 64 ci
        int co_l = e & 63, bc = e >> 6;
        int cell;
        if (bc < 14) cell = bc;
        else if (bc < 28) cell = 182 + (bc - 14);
        else { int r = bc - 28; cell = (1 + (r >> 1)) * 14 + ((r & 1) * 13); }
        p2u[((size_t)i * 196 + cell) * 128 + co0 + co_l] = 0;
    }
}

// ------------------------- conv3: MFMA GEMM -> h3 fp32 ---------------------
// grid (96 image-quads, 4 co-quarters), block 576 = 9 waves; wave 64m x 64n.
// LDS: imgS 0..62720 (784 rows * 80B), sbw3 62720..108800 (576 rows * 80B),
//      sxq3 108800 (4*144 f32), wsqh3 111104 (64 f32), sS3 111360 (784 f32)
__global__ __launch_bounds__(576, 3) void conv3_kernel(
        const unsigned short* __restrict__ p2u, const unsigned short* __restrict__ w3s,
        const float* __restrict__ S3, const float* __restrict__ triw,
        const float* __restrict__ crb, const float* __restrict__ wsq,
        float* __restrict__ h3) {
    extern __shared__ char sm[];
    float* sxq3  = (float*)(sm + 108800);
    float* wsqh3 = (float*)(sm + 111104);
    float* sS3   = (float*)(sm + 111360);

    int g = blockIdx.x;
    int i0 = g * 4;
    int t = i0 / 128;
    int co0 = blockIdx.y * 64;
    int tid = threadIdx.x;
    int w = tid >> 6, l = tid & 63;
    int lm = l & 15, q = l >> 4;

    for (int e = tid; e < 784; e += 576) {
        int il = e / 196, cell = e % 196;
        int yy = cell / 14, xx = cell % 14;
        sS3[e] = (yy >= 1 && yy <= 12 && xx >= 1 && xx <= 12)
                     ? S3[(size_t)(i0 + il) * 144 + (yy - 1) * 12 + (xx - 1)] : 0.f;
    }
    if (tid < 64) wsqh3[tid] = wsq[576 + t * 256 + co0 + tid];
    __syncthreads();
    if (tid < 576) {
        int il = tid / 144, s = tid % 144;
        int oy = s / 12, ox = s % 12;
        float sum = 0.f;
#pragma unroll
        for (int ky = 0; ky < 3; ++ky)
#pragma unroll
            for (int kx = 0; kx < 3; ++kx)
                sum += sS3[il * 196 + (oy + ky) * 14 + (ox + kx)];
        sxq3[tid] = sum;
    }

    int posA[4], img_l[4], s0a[4];
#pragma unroll
    for (int mt = 0; mt < 4; ++mt) {
        int tb = w * 64 + mt * 16;
        int il = tb / 144, s0 = tb % 144;
        int s = s0 + lm;
        posA[mt] = il * 196 + (s / 12) * 14 + (s % 12);
        img_l[mt] = il; s0a[mt] = s0;
    }

    f32x4 zz; zz[0] = 0.f; zz[1] = 0.f; zz[2] = 0.f; zz[3] = 0.f;
    f32x4 acc[4][4];
#pragma unroll
    for (int a = 0; a < 4; ++a)
#pragma unroll
        for (int bb = 0; bb < 4; ++bb) acc[a][bb] = zz;

    for (int ks = 0; ks < 4; ++ks) {
        __syncthreads();
        for (int d = tid; d < 3136; d += 576) {      // imgS: 4img x 196 x 32ci
            int cg = d >> 2, c4 = d & 3;
            int il = cg / 196, cell = cg % 196;
            const uint4* gp = (const uint4*)(p2u + ((size_t)(i0 + il) * 196 + cell) * 128 + ks * 32);
            *(uint4*)(sm + cg * 80 + c4 * 16) = gp[c4];
        }
        for (int d = tid; d < 2304; d += 576) {      // sbw3: 9kk x 64co x 32ci
            int row = d >> 2, c4 = d & 3;
            int kk = row >> 6, n = row & 63;
            const uint4* gp = (const uint4*)(w3s + ((size_t)(t * 9 + kk) * 256 + co0 + n) * 128 + ks * 32);
            *(uint4*)(sm + 62720 + row * 80 + c4 * 16) = gp[c4];
        }
        __syncthreads();
#pragma unroll 1
        for (int kk = 0; kk < 9; ++kk) {
            int kof = (kk / 3) * 14 + (kk % 3);
            bf16x8 aF[4];
#pragma unroll
            for (int mt = 0; mt < 4; ++mt)
                aF[mt] = *(const bf16x8*)(sm + (posA[mt] + kof) * 80 + q * 16);
#pragma unroll
            for (int nt = 0; nt < 4; ++nt) {
                bf16x8 bF = *(const bf16x8*)(sm + 62720 + (kk * 64 + nt * 16 + lm) * 80 + q * 16);
                acc[0][nt] = __builtin_amdgcn_mfma_f32_16x16x32_bf16(aF[0], bF, acc[0][nt], 0, 0, 0);
                acc[1][nt] = __builtin_amdgcn_mfma_f32_16x16x32_bf16(aF[1], bF, acc[1][nt], 0, 0, 0);
                acc[2][nt] = __builtin_amdgcn_mfma_f32_16x16x32_bf16(aF[2], bF, acc[2][nt], 0, 0, 0);
                acc[3][nt] = __builtin_amdgcn_mfma_f32_16x16x32_bf16(aF[3], bF, acc[3][nt], 0, 0, 0);
            }
        }
    }
    __syncthreads();   // imgS dead -> per-wave transpose tiles

    float tw = triw[t * 3 + 2], itw = 1.f / tw, cb = crb[t * 3 + 2];
    float* tile = (float*)(sm + w * 1280);           // 16 x 20 floats, wave-private
#pragma unroll
    for (int mt = 0; mt < 4; ++mt) {
        int il = img_l[mt], s0 = s0a[mt];
        int bidx = (i0 + il) - t * 128;
        float* gbase = h3 + (size_t)bidx * 110592 + (size_t)t * 36864;
#pragma unroll
        for (int nt = 0; nt < 4; ++nt) {
            float wq = wsqh3[nt * 16 + lm];
#pragma unroll
            for (int r = 0; r < 4; ++r) {
                float d = sxq3[il * 144 + s0 + q * 4 + r] - 2.f * acc[mt][nt][r] + wq;
                d = fminf(fmaxf(d, 0.f), tw);
                float h = 1.f - d * itw;
                h = (h >= cb) ? h : 0.f;
                tile[lm * 20 + q * 4 + r] = h;       // [co_l][s_l]
            }
            f32x4 v = *(const f32x4*)(tile + (l >> 2) * 20 + (l & 3) * 4);
            *(f32x4*)(gbase + (size_t)(co0 + nt * 16 + (l >> 2)) * 144 + s0 + (l & 3) * 4) = v;
        }
    }
}

// ------------------------- FC: K-split partials + reduce -------------------
__global__ __launch_bounds__(256) void fc_partial_kernel(
        const float* __restrict__ h3, const float* __restrict__ fcw,
        float* __restrict__ part) {
    __shared__ float sH[128 * 49];
    __shared__ float sWf[104 * 48];

    int kb = blockIdx.x;
    int tid = threadIdx.x;
    int f0 = kb * 432;
    int bg = tid & 31, og = tid >> 5;
    int b0 = bg * 4, o0 = og * 13;

    float acc[4][13];
#pragma unroll
    for (int i = 0; i < 4; ++i)
#pragma unroll
        for (int j = 0; j < 13; ++j) acc[i][j] = 0.f;

    for (int fc = 0; fc < 9; ++fc) {
        int fbase = f0 + fc * 48;
        __syncthreads();
        for (int idx = tid; idx < 128 * 48; idx += 256) {
            int bb = idx / 48, ff = idx % 48;
            sH[bb * 49 + ff] = h3[(size_t)bb * 110592 + fbase + ff];
        }
        for (int idx = tid; idx < 104 * 48; idx += 256) {
            int oo = idx / 48, ff = idx % 48;
            sWf[idx] = (oo < 100) ? fcw[(size_t)oo * 110592 + fbase + ff] : 0.f;
        }
        __syncthreads();
#pragma unroll 4
        for (int ff = 0; ff < 48; ++ff) {
            float hv[4];
#pragma unroll
            for (int ib = 0; ib < 4; ++ib) hv[ib] = sH[(b0 + ib) * 49 + ff];
#pragma unroll
            for (int io = 0; io < 13; ++io) {
                float wv = sWf[(o0 + io) * 48 + ff];
#pragma unroll
                for (int ib = 0; ib < 4; ++ib) acc[ib][io] += hv[ib] * wv;
            }
        }
    }

    int on = (og == 7) ? 9 : 13;
    float* pb = part + (size_t)kb * 12800;
    for (int ib = 0; ib < 4; ++ib)
        for (int io = 0; io < on; ++io)
            pb[(b0 + ib) * 100 + o0 + io] = acc[ib][io];
}

__global__ void fc_reduce_kernel(const float* __restrict__ part,
                                 const float* __restrict__ fcb,
                                 float* __restrict__ out) {
    int gid = blockIdx.x * 256 + threadIdx.x;
    if (gid >= 12800) return;
    int o = gid % 100;
    float s = fcb[o];
    for (int kb = 0; kb < 256; ++kb) s += part[(size_t)kb * 12800 + gid];
    out[gid] = s;
}

// ---------------------------------------------------------------------------
extern "C" void kernel_launch(void* const* d_in, const int* in_sizes, int n_in,
                              void* d_out, int out_size, void* d_ws, size_t ws_size,
                              hipStream_t stream) {
    const float* x    = (const float*)d_in[0];
    const float* W1   = (const float*)d_in[1];
    const float* W2   = (const float*)d_in[2];
    const float* W3   = (const float*)d_in[3];
    const float* triw = (const float*)d_in[4];
    const float* crb  = (const float*)d_in[5];
    const float* alp  = (const float*)d_in[6];
    const float* fcw  = (const float*)d_in[7];
    const float* fcb  = (const float*)d_in[8];
    float* out = (float*)d_out;
    float* ws  = (float*)d_ws;

    unsigned short* p1u = (unsigned short*)ws;                  // aliased by h3 later
    unsigned short* p2u = (unsigned short*)(ws + OFF_P2CL);
    float* S2  = ws + OFF_S2;
    float* S3  = ws + OFF_S3;
    float* wsq = ws + OFF_WSQ;
    unsigned short* w2s = (unsigned short*)(ws + OFF_W2S);
    unsigned short* w3s = (unsigned short*)(ws + OFF_W3S);
    float* fcp = ws + OFF_FCP;
    float* h3  = ws;                                            // p1cl dead by then

    hipFuncSetAttribute((const void*)conv2_kernel,
                        hipFuncAttributeMaxDynamicSharedMemorySize, 130256);
    hipFuncSetAttribute((const void*)conv3_kernel,
                        hipFuncAttributeMaxDynamicSharedMemorySize, 114496);

    prep_kernel<<<dim3(432), dim3(256), 0, stream>>>(W1, W2, W3, w2s, w3s, wsq);
    conv1_kernel<<<dim3(384, 4), dim3(256), 0, stream>>>(x, W1, triw, crb, alp, wsq, p1u);
    s2_kernel<<<dim3(384), dim3(576), 0, stream>>>(p1u, S2);
    conv2_kernel<<<dim3(384, 2), dim3(576), 130256, stream>>>(p1u, w2s, S2, triw, crb, alp, wsq, p2u);
    s3_kernel<<<dim3(96), dim3(576), 0, stream>>>(p2u, S3);
    conv3_kernel<<<dim3(96, 4), dim3(576), 114496, stream>>>(p2u, w3s, S3, triw, crb, wsq, h3);
    fc_partial_kernel<<<dim3(256), dim3(256), 0, stream>>>(h3, fcw, fcp);
    fc_reduce_kernel<<<dim3(50), dim3(256), 0, stream>>>(fcp, fcb, out);
}

// Round 3
// 424.170 us; speedup vs baseline: 8.3586x; 1.5795x over previous
//
#include <hip/hip_runtime.h>
#include <hip/hip_bf16.h>

// ---------------------------------------------------------------------------
// SFMCNN: conv1 register-blocked fp32 (fuses S2), conv2/conv3 bf16 MFMA GEMM,
// FC as LDS-free bf16 MFMA K-split GEMM (h3 stored bf16 by conv3, fcw
// converted fp32->bf16 in-register).
//
// ws layout (float offsets):
//   p1u  [0, 8306688)          bf16 (3,128,26,26,64) halo-baked; h3bf aliases [0,7077888)
//   p2u  [8306688, +4816896)   bf16 (3,128,14,14,128) halo-baked
//   S2   [13123584, +221184)   fp32 (3*128, 576)
//   S3   [13344768, +55296)
//   wsq  [13400064, +1344)
//   w2s  [13401408, +110592)   bf16 (3,9,128co,64ci)
//   w3s  [13512000, +442368)   bf16 (3,9,256co,128ci)
//   part [13954368, +6193152)  fp32 (432,128,112) FC partials (also aliases
//                              p2u..w3s zone is dead by FC time -- no overlap anyway)
// total 20,147,520 floats = 80.6 MB
// ---------------------------------------------------------------------------

static const size_t OFF_P2CL = 8306688;
static const size_t OFF_S2   = 13123584;
static const size_t OFF_S3   = 13344768;
static const size_t OFF_WSQ  = 13400064;
static const size_t OFF_W2S  = 13401408;
static const size_t OFF_W3S  = 13512000;
static const size_t OFF_PART = 13954368;

typedef short bf16x8 __attribute__((ext_vector_type(8)));
typedef float f32x4 __attribute__((ext_vector_type(4)));

__device__ __forceinline__ unsigned short f2bf(float f) {
    union { float f; unsigned u; } v; v.f = f;
    unsigned r = (v.u + 0x7FFFu + ((v.u >> 16) & 1u)) >> 16;
    return (unsigned short)r;
}
__device__ __forceinline__ float bf2f(unsigned short h) {
    union { unsigned u; float f; } v; v.u = ((unsigned)h) << 16;
    return v.f;
}
__device__ __forceinline__ unsigned pkbf(float a, float b) {
    union { __hip_bfloat162 h2; unsigned u; } c;
    c.h2 = __float22bfloat162_rn(make_float2(a, b));
    return c.u;
}

// ------------------------- prep: W2s/W3s bf16 reorder + wsq ----------------
__global__ __launch_bounds__(256) void prep_kernel(
        const float* __restrict__ W1, const float* __restrict__ W2,
        const float* __restrict__ W3, unsigned short* __restrict__ w2s,
        unsigned short* __restrict__ w3s, float* __restrict__ wsq) {
    int gid = blockIdx.x * 256 + threadIdx.x;   // grid 432 -> 110592 threads
#pragma unroll
    for (int k = 0; k < 2; ++k) {               // W2s: 221184 = (t,kk,co,ci)
        int e = gid * 2 + k;
        int t = e / 73728, r = e % 73728;
        int kk = r / 8192; r %= 8192;
        int co = r / 64, ci = r % 64;
        w2s[e] = f2bf(W2[(size_t)(t * 128 + co) * 576 + ci * 9 + kk]);
    }
#pragma unroll
    for (int k = 0; k < 8; ++k) {               // W3s: 884736
        int e = gid * 8 + k;
        int t = e / 294912, r = e % 294912;
        int kk = r / 32768; r %= 32768;
        int co = r / 128, ci = r % 128;
        w3s[e] = f2bf(W3[(size_t)(t * 256 + co) * 1152 + ci * 9 + kk]);
    }
    if (gid < 1344) {
        int t = gid / 448, r = gid % 448;
        if (r < 64) {
            const float* w = W1 + (size_t)(t * 64 + r) * 25; float s = 0.f;
            for (int k = 0; k < 25; ++k) s += w[k] * w[k];
            wsq[t * 64 + r] = s;
        } else if (r < 192) {
            int c = r - 64;
            const float* w = W2 + (size_t)(t * 128 + c) * 576; float s = 0.f;
            for (int k = 0; k < 576; ++k) { float v = bf2f(f2bf(w[k])); s += v * v; }
            wsq[192 + t * 128 + c] = s;
        } else {
            int c = r - 192;
            const float* w = W3 + (size_t)(t * 256 + c) * 1152; float s = 0.f;
            for (int k = 0; k < 1152; ++k) { float v = bf2f(f2bf(w[k])); s += v * v; }
            wsq[576 + t * 256 + c] = s;
        }
    }
}

// ------------------------- conv1: register-blocked, fuses S2 ---------------
__device__ __forceinline__ void conv1_ch(const float xv[8][8], const float* xsqr,
        const float* wp, float wq, float tw, float itw, float cb,
        const float* apw, float pooled[4]) {
    float acc[16];
#pragma unroll
    for (int i = 0; i < 16; ++i) acc[i] = 0.f;
#pragma unroll
    for (int ky = 0; ky < 5; ++ky)
#pragma unroll
        for (int kx = 0; kx < 5; ++kx) {
            float wv = wp[ky * 5 + kx];
#pragma unroll
            for (int ii = 0; ii < 4; ++ii)
#pragma unroll
                for (int jj = 0; jj < 4; ++jj)
                    acc[ii * 4 + jj] = fmaf(xv[ii + ky][jj + kx], wv, acc[ii * 4 + jj]);
        }
#pragma unroll
    for (int c2 = 0; c2 < 4; ++c2) pooled[c2] = 0.f;
#pragma unroll
    for (int ii = 0; ii < 4; ++ii)
#pragma unroll
        for (int jj = 0; jj < 4; ++jj) {
            float d = fmaf(-2.f, acc[ii * 4 + jj], xsqr[ii * 4 + jj]) + wq;
            d = fminf(fmaxf(d, 0.f), tw);
            float h = 1.f - d * itw;
            h = (h >= cb) ? h : 0.f;
            int pc = (ii >> 1) * 2 + (jj >> 1);
            pooled[pc] = fmaf(h, apw[(ii & 1) * 2 + (jj & 1)], pooled[pc]);
        }
}

// grid 384 (one image each), block 576 = 144 spatial tiles x 4 ch-groups.
__global__ __launch_bounds__(576, 1) void conv1_kernel(
        const float* __restrict__ x, const float* __restrict__ W1,
        const float* __restrict__ triw, const float* __restrict__ crb,
        const float* __restrict__ alp, const float* __restrict__ wsqb,
        unsigned short* __restrict__ p1u, float* __restrict__ S2) {
    __shared__ float simg[52 * 52];
    __shared__ float srs[52 * 48];
    __shared__ float sxq[48 * 48];
    __shared__ float sw[64 * 25];
    __shared__ float swq[64];
    __shared__ float sS2[576];

    int bi = blockIdx.x;            // image index t*128+b
    int t = bi / 128, b = bi % 128;
    int tid = threadIdx.x;
    const float* xim = x + (size_t)(b * 3 + t) * 2304;

    for (int idx = tid; idx < 52 * 52; idx += 576) {
        int y = idx / 52 - 2, xx = idx % 52 - 2;
        simg[idx] = (y >= 0 && y < 48 && xx >= 0 && xx < 48) ? xim[y * 48 + xx] : 0.f;
    }
    for (int idx = tid; idx < 1600; idx += 576) sw[idx] = W1[(size_t)t * 1600 + idx];
    if (tid < 64) swq[tid] = wsqb[t * 64 + tid];
    if (tid < 576) sS2[tid] = 0.f;
    __syncthreads();

    for (int idx = tid; idx < 52 * 48; idx += 576) {
        int i = idx / 48, ox = idx % 48;
        const float* r = &simg[i * 52 + ox];
        float s = 0.f;
#pragma unroll
        for (int j = 0; j < 5; ++j) s += r[j] * r[j];
        srs[idx] = s;
    }
    __syncthreads();
    for (int idx = tid; idx < 48 * 48; idx += 576) {
        int oy = idx / 48, ox = idx % 48;
        float s = 0.f;
#pragma unroll
        for (int i = 0; i < 5; ++i) s += srs[(oy + i) * 48 + ox];
        sxq[idx] = s;
    }
    __syncthreads();

    int chg = tid / 144, tile = tid % 144;
    int ty = tile / 12, tx = tile % 12;
    int oy0 = ty * 4, ox0 = tx * 4;

    float xv[8][8];
#pragma unroll
    for (int r = 0; r < 8; ++r) {
        f32x4 a = *(const f32x4*)&simg[(oy0 + r) * 52 + ox0];
        f32x4 c = *(const f32x4*)&simg[(oy0 + r) * 52 + ox0 + 4];
#pragma unroll
        for (int j = 0; j < 4; ++j) { xv[r][j] = a[j]; xv[r][4 + j] = c[j]; }
    }
    float xsqr[16];
#pragma unroll
    for (int ii = 0; ii < 4; ++ii)
#pragma unroll
        for (int jj = 0; jj < 4; ++jj)
            xsqr[ii * 4 + jj] = sxq[(oy0 + ii) * 48 + ox0 + jj];

    float tw = triw[t * 3 + 0], itw = 1.f / tw;
    float cb = crb[t * 3 + 0];
    float al = alp[t * 2 + 0];
    float apw[4] = {al * al * al * 0.25f, al * al * 0.25f, al * 0.25f, 0.25f};

    unsigned outp[4][8];
    float s2a[4] = {0.f, 0.f, 0.f, 0.f};

#pragma unroll 1
    for (int cp = 0; cp < 8; ++cp) {
        int ch0 = chg * 16 + cp * 2;
        float p0[4], p1[4];
        conv1_ch(xv, xsqr, &sw[ch0 * 25], swq[ch0], tw, itw, cb, apw, p0);
        conv1_ch(xv, xsqr, &sw[(ch0 + 1) * 25], swq[ch0 + 1], tw, itw, cb, apw, p1);
#pragma unroll
        for (int c2 = 0; c2 < 4; ++c2) {
            unsigned short u0 = f2bf(p0[c2]), u1 = f2bf(p1[c2]);
            float v0 = bf2f(u0), v1 = bf2f(u1);
            s2a[c2] += v0 * v0 + v1 * v1;
            outp[c2][cp] = (unsigned)u0 | ((unsigned)u1 << 16);
        }
    }

    size_t imgbase = (size_t)bi * 43264;
#pragma unroll
    for (int c2 = 0; c2 < 4; ++c2) {
        int py = ty * 2 + (c2 >> 1), px = tx * 2 + (c2 & 1);
        int cell = (py + 1) * 26 + px + 1;
        uint4* gp = (uint4*)(p1u + imgbase + (size_t)cell * 64 + chg * 16);
        uint4 v0; v0.x = outp[c2][0]; v0.y = outp[c2][1]; v0.z = outp[c2][2]; v0.w = outp[c2][3];
        uint4 v1; v1.x = outp[c2][4]; v1.y = outp[c2][5]; v1.z = outp[c2][6]; v1.w = outp[c2][7];
        gp[0] = v0; gp[1] = v1;
        atomicAdd(&sS2[py * 24 + px], s2a[c2]);
    }
    __syncthreads();
    S2[(size_t)bi * 576 + tid] = sS2[tid];

    uint4 z; z.x = 0; z.y = 0; z.z = 0; z.w = 0;
    for (int e = tid; e < 800; e += 576) {       // 100 border cells x 8 uint4
        int bc = e >> 3, c8 = e & 7;
        int cell;
        if (bc < 26) cell = bc;
        else if (bc < 52) cell = 650 + (bc - 26);
        else { int r = bc - 52; cell = (1 + (r >> 1)) * 26 + ((r & 1) * 25); }
        *(uint4*)(p1u + imgbase + (size_t)cell * 64 + c8 * 8) = z;
    }
}

// ------------------------- s3 (from bf16-rounded values) -------------------
__device__ __forceinline__ float sq8(uint4 u) {
    float s = 0.f;
    const unsigned* p = (const unsigned*)&u;
#pragma unroll
    for (int j = 0; j < 4; ++j) {
        float a = bf2f((unsigned short)(p[j] & 0xFFFFu));
        float b = bf2f((unsigned short)(p[j] >> 16));
        s += a * a + b * b;
    }
    return s;
}

__global__ __launch_bounds__(576) void s3_kernel(const unsigned short* __restrict__ p2u,
                                                 float* __restrict__ S3) {
    int g = blockIdx.x;                 // 0..95
    int tid = threadIdx.x;
    int il = tid / 144, s = tid % 144;
    int i = g * 4 + il;
    int cell = (s / 12 + 1) * 14 + (s % 12) + 1;
    const uint4* gp = (const uint4*)(p2u + ((size_t)i * 196 + cell) * 128);
    float acc = 0.f;
#pragma unroll
    for (int k = 0; k < 16; ++k) acc += sq8(gp[k]);
    S3[(size_t)i * 144 + s] = acc;
}

// ------------------------- conv2: MFMA GEMM + pool -> p2cl -----------------
__global__ __launch_bounds__(576, 3) void conv2_kernel(
        const unsigned short* __restrict__ p1u, const unsigned short* __restrict__ w2s,
        const float* __restrict__ S2, const float* __restrict__ triw,
        const float* __restrict__ crb, const float* __restrict__ alp,
        const float* __restrict__ wsq, unsigned short* __restrict__ p2u) {
    extern __shared__ char sm[];
    float* sS   = (float*)(sm + 124992);
    float* sxq  = (float*)(sm + 127696);
    float* wsqh = (float*)(sm + 130000);
    float* pbuf = (float*)sm;

    int i = blockIdx.x;
    int t = i / 128;
    int co0 = blockIdx.y * 64;
    int tid = threadIdx.x;
    int w = tid >> 6, l = tid & 63;
    int lm = l & 15, q = l >> 4;

    {   // stage image: 676 cells x 64ci bf16 -> rows padded to 72 ushorts
        const uint4* gsrc = (const uint4*)(p1u + (size_t)i * 43264);
        for (int d = tid; d < 5408; d += 576) {
            int cell = d >> 3, c8 = d & 7;
            *(uint4*)(sm + cell * 144 + c8 * 16) = gsrc[(size_t)cell * 8 + c8];
        }
    }
    for (int e = tid; e < 676; e += 576) {
        int yy = e / 26, xx = e % 26;
        sS[e] = (yy >= 1 && yy <= 24 && xx >= 1 && xx <= 24)
                    ? S2[(size_t)i * 576 + (yy - 1) * 24 + (xx - 1)] : 0.f;
    }
    if (tid < 64) wsqh[tid] = wsq[192 + t * 128 + co0 + tid];
    __syncthreads();
    if (tid < 576) {
        int oy = tid / 24, ox = tid % 24;
        float s = 0.f;
#pragma unroll
        for (int ky = 0; ky < 3; ++ky)
#pragma unroll
            for (int kx = 0; kx < 3; ++kx) s += sS[(oy + ky) * 26 + ox + kx];
        sxq[tid] = s;
    }

    int posA[4], oyq[4], oxq[4];
#pragma unroll
    for (int mt = 0; mt < 4; ++mt) {
        int m = w * 64 + mt * 16 + lm;
        posA[mt] = (m / 24) * 26 + (m % 24);
        int sb = w * 64 + mt * 16 + q * 4;
        oyq[mt] = sb / 24; oxq[mt] = sb % 24;
    }

    f32x4 zz; zz[0] = 0.f; zz[1] = 0.f; zz[2] = 0.f; zz[3] = 0.f;
    f32x4 acc[4][4];
#pragma unroll
    for (int a = 0; a < 4; ++a)
#pragma unroll
        for (int bb = 0; bb < 4; ++bb) acc[a][bb] = zz;

    const unsigned short* w2base = w2s + (size_t)t * 9 * 128 * 64;

    for (int kg = 0; kg < 3; ++kg) {
        __syncthreads();
        for (int d = tid; d < 1536; d += 576) {     // 3 kk x 64 co x 64 ci
            int kkl = d / 512, r = d % 512;
            int n = r >> 3, c8 = r & 7;
            const uint4* g = (const uint4*)(w2base + ((size_t)(kg * 3 + kkl) * 128 + co0 + n) * 64);
            *(uint4*)(sm + 97344 + (kkl * 64 + n) * 144 + c8 * 16) = g[c8];
        }
        __syncthreads();
#pragma unroll
        for (int kkl = 0; kkl < 3; ++kkl) {
            int kk = kg * 3 + kkl;
            int kof = (kk / 3) * 26 + (kk % 3);
#pragma unroll
            for (int ks = 0; ks < 2; ++ks) {
                bf16x8 aF[4];
#pragma unroll
                for (int mt = 0; mt < 4; ++mt)
                    aF[mt] = *(const bf16x8*)(sm + (posA[mt] + kof) * 144 + ks * 64 + q * 16);
#pragma unroll
                for (int nt = 0; nt < 4; ++nt) {
                    bf16x8 bF = *(const bf16x8*)(sm + 97344 + (kkl * 64 + nt * 16 + lm) * 144 + ks * 64 + q * 16);
                    acc[0][nt] = __builtin_amdgcn_mfma_f32_16x16x32_bf16(aF[0], bF, acc[0][nt], 0, 0, 0);
                    acc[1][nt] = __builtin_amdgcn_mfma_f32_16x16x32_bf16(aF[1], bF, acc[1][nt], 0, 0, 0);
                    acc[2][nt] = __builtin_amdgcn_mfma_f32_16x16x32_bf16(aF[2], bF, acc[2][nt], 0, 0, 0);
                    acc[3][nt] = __builtin_amdgcn_mfma_f32_16x16x32_bf16(aF[3], bF, acc[3][nt], 0, 0, 0);
                }
            }
        }
    }
    __syncthreads();   // img dead -> pbuf alias

    float tw = triw[t * 3 + 1], itw = 1.f / tw, cb = crb[t * 3 + 1], al = alp[t * 2 + 1];
    float apw[4] = {al * al * al * 0.25f, al * al * 0.25f, al * 0.25f, 0.25f};
#pragma unroll
    for (int mt = 0; mt < 4; ++mt) {
        int sb = w * 64 + mt * 16 + q * 4;
        int cell = oyq[mt] * 12 + (oxq[mt] >> 1);
        int oybit = (oyq[mt] & 1) << 1;
#pragma unroll
        for (int nt = 0; nt < 4; ++nt) {
            int n = nt * 16 + lm;
            float wq = wsqh[n];
            float hw[4];
#pragma unroll
            for (int r = 0; r < 4; ++r) {
                float d = sxq[sb + r] - 2.f * acc[mt][nt][r] + wq;
                d = fminf(fmaxf(d, 0.f), tw);
                float h = 1.f - d * itw;
                h = (h >= cb) ? h : 0.f;
                hw[r] = h * apw[oybit | (r & 1)];
            }
            pbuf[cell * 65 + n] = hw[0] + hw[1];
            pbuf[(cell + 1) * 65 + n] = hw[2] + hw[3];
        }
    }
    __syncthreads();
    for (int e = tid; e < 9216; e += 576) {
        int co_l = e & 63, pp = e >> 6;
        int py = pp / 12, px = pp % 12;
        float v = pbuf[((2 * py) * 12 + px) * 65 + co_l] +
                  pbuf[((2 * py + 1) * 12 + px) * 65 + co_l];
        p2u[((size_t)i * 196 + (py + 1) * 14 + px + 1) * 128 + co0 + co_l] = f2bf(v);
    }
    for (int e = tid; e < 3328; e += 576) {      // 52 border cells x 64 ci
        int co_l = e & 63, bc = e >> 6;
        int cell;
        if (bc < 14) cell = bc;
        else if (bc < 28) cell = 182 + (bc - 14);
        else { int r = bc - 28; cell = (1 + (r >> 1)) * 14 + ((r & 1) * 13); }
        p2u[((size_t)i * 196 + cell) * 128 + co0 + co_l] = 0;
    }
}

// ------------------------- conv3: MFMA GEMM -> h3 bf16 ---------------------
__global__ __launch_bounds__(576, 3) void conv3_kernel(
        const unsigned short* __restrict__ p2u, const unsigned short* __restrict__ w3s,
        const float* __restrict__ S3, const float* __restrict__ triw,
        const float* __restrict__ crb, const float* __restrict__ wsq,
        unsigned short* __restrict__ h3bf) {
    extern __shared__ char sm[];
    float* sxq3  = (float*)(sm + 108800);
    float* wsqh3 = (float*)(sm + 111104);
    float* sS3   = (float*)(sm + 111360);

    int g = blockIdx.x;
    int i0 = g * 4;
    int t = i0 / 128;
    int co0 = blockIdx.y * 64;
    int tid = threadIdx.x;
    int w = tid >> 6, l = tid & 63;
    int lm = l & 15, q = l >> 4;

    for (int e = tid; e < 784; e += 576) {
        int il = e / 196, cell = e % 196;
        int yy = cell / 14, xx = cell % 14;
        sS3[e] = (yy >= 1 && yy <= 12 && xx >= 1 && xx <= 12)
                     ? S3[(size_t)(i0 + il) * 144 + (yy - 1) * 12 + (xx - 1)] : 0.f;
    }
    if (tid < 64) wsqh3[tid] = wsq[576 + t * 256 + co0 + tid];
    __syncthreads();
    if (tid < 576) {
        int il = tid / 144, s = tid % 144;
        int oy = s / 12, ox = s % 12;
        float sum = 0.f;
#pragma unroll
        for (int ky = 0; ky < 3; ++ky)
#pragma unroll
            for (int kx = 0; kx < 3; ++kx)
                sum += sS3[il * 196 + (oy + ky) * 14 + (ox + kx)];
        sxq3[tid] = sum;
    }

    int posA[4], img_l[4], s0a[4];
#pragma unroll
    for (int mt = 0; mt < 4; ++mt) {
        int tb = w * 64 + mt * 16;
        int il = tb / 144, s0 = tb % 144;
        int s = s0 + lm;
        posA[mt] = il * 196 + (s / 12) * 14 + (s % 12);
        img_l[mt] = il; s0a[mt] = s0;
    }

    f32x4 zz; zz[0] = 0.f; zz[1] = 0.f; zz[2] = 0.f; zz[3] = 0.f;
    f32x4 acc[4][4];
#pragma unroll
    for (int a = 0; a < 4; ++a)
#pragma unroll
        for (int bb = 0; bb < 4; ++bb) acc[a][bb] = zz;

    for (int ks = 0; ks < 4; ++ks) {
        __syncthreads();
        for (int d = tid; d < 3136; d += 576) {      // imgS: 4img x 196 x 32ci
            int cg = d >> 2, c4 = d & 3;
            int il = cg / 196, cell = cg % 196;
            const uint4* gp = (const uint4*)(p2u + ((size_t)(i0 + il) * 196 + cell) * 128 + ks * 32);
            *(uint4*)(sm + cg * 80 + c4 * 16) = gp[c4];
        }
        for (int d = tid; d < 2304; d += 576) {      // sbw3: 9kk x 64co x 32ci
            int row = d >> 2, c4 = d & 3;
            int kk = row >> 6, n = row & 63;
            const uint4* gp = (const uint4*)(w3s + ((size_t)(t * 9 + kk) * 256 + co0 + n) * 128 + ks * 32);
            *(uint4*)(sm + 62720 + row * 80 + c4 * 16) = gp[c4];
        }
        __syncthreads();
#pragma unroll 1
        for (int kk = 0; kk < 9; ++kk) {
            int kof = (kk / 3) * 14 + (kk % 3);
            bf16x8 aF[4];
#pragma unroll
            for (int mt = 0; mt < 4; ++mt)
                aF[mt] = *(const bf16x8*)(sm + (posA[mt] + kof) * 80 + q * 16);
#pragma unroll
            for (int nt = 0; nt < 4; ++nt) {
                bf16x8 bF = *(const bf16x8*)(sm + 62720 + (kk * 64 + nt * 16 + lm) * 80 + q * 16);
                acc[0][nt] = __builtin_amdgcn_mfma_f32_16x16x32_bf16(aF[0], bF, acc[0][nt], 0, 0, 0);
                acc[1][nt] = __builtin_amdgcn_mfma_f32_16x16x32_bf16(aF[1], bF, acc[1][nt], 0, 0, 0);
                acc[2][nt] = __builtin_amdgcn_mfma_f32_16x16x32_bf16(aF[2], bF, acc[2][nt], 0, 0, 0);
                acc[3][nt] = __builtin_amdgcn_mfma_f32_16x16x32_bf16(aF[3], bF, acc[3][nt], 0, 0, 0);
            }
        }
    }
    __syncthreads();   // imgS dead -> per-wave transpose tiles

    float tw = triw[t * 3 + 2], itw = 1.f / tw, cb = crb[t * 3 + 2];
    float* tile = (float*)(sm + w * 1280);           // 16 x 20 floats, wave-private
#pragma unroll
    for (int mt = 0; mt < 4; ++mt) {
        int il = img_l[mt], s0 = s0a[mt];
        int bidx = (i0 + il) - t * 128;
        unsigned short* gbase = h3bf + (size_t)bidx * 110592 + (size_t)t * 36864;
#pragma unroll
        for (int nt = 0; nt < 4; ++nt) {
            float wq = wsqh3[nt * 16 + lm];
#pragma unroll
            for (int r = 0; r < 4; ++r) {
                float d = sxq3[il * 144 + s0 + q * 4 + r] - 2.f * acc[mt][nt][r] + wq;
                d = fminf(fmaxf(d, 0.f), tw);
                float h = 1.f - d * itw;
                h = (h >= cb) ? h : 0.f;
                tile[lm * 20 + q * 4 + r] = h;       // [co_l][s_l]
            }
            f32x4 v = *(const f32x4*)(tile + (l >> 2) * 20 + (l & 3) * 4);
            uint2 uv; uv.x = pkbf(v[0], v[1]); uv.y = pkbf(v[2], v[3]);
            *(uint2*)(gbase + (size_t)(co0 + nt * 16 + (l >> 2)) * 144 + s0 + (l & 3) * 4) = uv;
        }
    }
}

// ------------------------- FC: LDS-free bf16 MFMA K-split ------------------
// grid 432 (K-slab 256 each), block 512 = 8 waves; wave w owns m rows w*16..+15,
// all 112 n (100 padded). A-frags 16B direct from h3bf; B converted fp32->bf16.
__global__ __launch_bounds__(512) void fc_kernel(
        const unsigned short* __restrict__ h3bf, const float* __restrict__ fcw,
        float* __restrict__ part) {
    int kb = blockIdx.x;
    int f0 = kb * 256;
    int tid = threadIdx.x;
    int w = tid >> 6, l = tid & 63;
    int lm = l & 15, q = l >> 4;

    const unsigned short* abase = h3bf + (size_t)(w * 16 + lm) * 110592 + f0 + q * 8;
    const float* brow[7];
#pragma unroll
    for (int nt = 0; nt < 7; ++nt) {
        int n = nt * 16 + lm;
        if (n > 99) n = 99;                      // pad rows duplicate row 99 (discarded)
        brow[nt] = fcw + (size_t)n * 110592 + f0 + q * 8;
    }

    f32x4 zz; zz[0] = 0.f; zz[1] = 0.f; zz[2] = 0.f; zz[3] = 0.f;
    f32x4 acc[7];
#pragma unroll
    for (int nt = 0; nt < 7; ++nt) acc[nt] = zz;

#pragma unroll 2
    for (int kc = 0; kc < 8; ++kc) {
        bf16x8 aF = *(const bf16x8*)(abase + kc * 32);
#pragma unroll
        for (int nt = 0; nt < 7; ++nt) {
            f32x4 b0 = *(const f32x4*)(brow[nt] + kc * 32);
            f32x4 b1 = *(const f32x4*)(brow[nt] + kc * 32 + 4);
            union { bf16x8 v; unsigned u[4]; } bF;
            bF.u[0] = pkbf(b0[0], b0[1]);
            bF.u[1] = pkbf(b0[2], b0[3]);
            bF.u[2] = pkbf(b1[0], b1[1]);
            bF.u[3] = pkbf(b1[2], b1[3]);
            acc[nt] = __builtin_amdgcn_mfma_f32_16x16x32_bf16(aF, bF.v, acc[nt], 0, 0, 0);
        }
    }

    float* pb = part + (size_t)kb * 14336;
#pragma unroll
    for (int nt = 0; nt < 7; ++nt)
#pragma unroll
        for (int r = 0; r < 4; ++r)
            pb[(w * 16 + q * 4 + r) * 112 + nt * 16 + lm] = acc[nt][r];
}

__global__ void fc_reduce_kernel(const float* __restrict__ part,
                                 const float* __restrict__ fcb,
                                 float* __restrict__ out) {
    int gid = blockIdx.x * 256 + threadIdx.x;
    if (gid >= 12800) return;
    int b = gid / 100, o = gid % 100;
    float s = fcb[o];
    const float* p = part + (size_t)b * 112 + o;
#pragma unroll 8
    for (int kb = 0; kb < 432; ++kb) s += p[(size_t)kb * 14336];
    out[gid] = s;
}

// ---------------------------------------------------------------------------
extern "C" void kernel_launch(void* const* d_in, const int* in_sizes, int n_in,
                              void* d_out, int out_size, void* d_ws, size_t ws_size,
                              hipStream_t stream) {
    const float* x    = (const float*)d_in[0];
    const float* W1   = (const float*)d_in[1];
    const float* W2   = (const float*)d_in[2];
    const float* W3   = (const float*)d_in[3];
    const float* triw = (const float*)d_in[4];
    const float* crb  = (const float*)d_in[5];
    const float* alp  = (const float*)d_in[6];
    const float* fcw  = (const float*)d_in[7];
    const float* fcb  = (const float*)d_in[8];
    float* out = (float*)d_out;
    float* ws  = (float*)d_ws;

    unsigned short* p1u = (unsigned short*)ws;
    unsigned short* p2u = (unsigned short*)(ws + OFF_P2CL);
    float* S2  = ws + OFF_S2;
    float* S3  = ws + OFF_S3;
    float* wsq = ws + OFF_WSQ;
    unsigned short* w2s = (unsigned short*)(ws + OFF_W2S);
    unsigned short* w3s = (unsigned short*)(ws + OFF_W3S);
    float* part = ws + OFF_PART;
    unsigned short* h3bf = (unsigned short*)ws;      // aliases p1u (dead by conv3)

    hipFuncSetAttribute((const void*)conv2_kernel,
                        hipFuncAttributeMaxDynamicSharedMemorySize, 130256);
    hipFuncSetAttribute((const void*)conv3_kernel,
                        hipFuncAttributeMaxDynamicSharedMemorySize, 114496);

    prep_kernel<<<dim3(432), dim3(256), 0, stream>>>(W1, W2, W3, w2s, w3s, wsq);
    conv1_kernel<<<dim3(384), dim3(576), 0, stream>>>(x, W1, triw, crb, alp, wsq, p1u, S2);
    conv2_kernel<<<dim3(384, 2), dim3(576), 130256, stream>>>(p1u, w2s, S2, triw, crb, alp, wsq, p2u);
    s3_kernel<<<dim3(96), dim3(576), 0, stream>>>(p2u, S3);
    conv3_kernel<<<dim3(96, 4), dim3(576), 114496, stream>>>(p2u, w3s, S3, triw, crb, wsq, h3bf);
    fc_kernel<<<dim3(432), dim3(512), 0, stream>>>(h3bf, fcw, part);
    fc_reduce_kernel<<<dim3(50), dim3(256), 0, stream>>>(part, fcb, out);
}

// Round 4
// 421.979 us; speedup vs baseline: 8.4020x; 1.0052x over previous
//
#include <hip/hip_runtime.h>
#include <hip/hip_bf16.h>

// ---------------------------------------------------------------------------
// SFMCNN: conv1 register-blocked fp32 (fuses S2, quarter-split for balance),
// conv2/conv3 bf16 MFMA GEMM, FC as LDS-free bf16 MFMA K-split GEMM.
//
// ws layout (float offsets):
//   p1u  [0, 8306688)          bf16 (3,128,26,26,64) halo-baked; h3bf aliases [0,7077888)
//   p2u  [8306688, +4816896)   bf16 (3,128,14,14,128) halo-baked
//   S2   [13123584, +221184)   fp32 (3*128, 576)
//   S3   [13344768, +55296)
//   wsq  [13400064, +1344)
//   w2s  [13401408, +110592)   bf16 (3,9,128co,64ci)
//   w3s  [13512000, +442368)   bf16 (3,9,256co,128ci)
//   part [13954368, +6193152)  fp32 (432,128,112) FC partials
//   part2[20147520, +102400)   fp32 (8,12800) stage-1 reduced partials
// total 20,249,920 floats = 81.0 MB
// ---------------------------------------------------------------------------

static const size_t OFF_P2CL = 8306688;
static const size_t OFF_S2   = 13123584;
static const size_t OFF_S3   = 13344768;
static const size_t OFF_WSQ  = 13400064;
static const size_t OFF_W2S  = 13401408;
static const size_t OFF_W3S  = 13512000;
static const size_t OFF_PART = 13954368;
static const size_t OFF_PART2= 20147520;

typedef short bf16x8 __attribute__((ext_vector_type(8)));
typedef float f32x4 __attribute__((ext_vector_type(4)));

__device__ __forceinline__ unsigned short f2bf(float f) {
    union { float f; unsigned u; } v; v.f = f;
    unsigned r = (v.u + 0x7FFFu + ((v.u >> 16) & 1u)) >> 16;
    return (unsigned short)r;
}
__device__ __forceinline__ float bf2f(unsigned short h) {
    union { unsigned u; float f; } v; v.u = ((unsigned)h) << 16;
    return v.f;
}
__device__ __forceinline__ unsigned pkbf(float a, float b) {
    union { __hip_bfloat162 h2; unsigned u; } c;
    c.h2 = __float22bfloat162_rn(make_float2(a, b));
    return c.u;
}

// ------------------------- prep: W2s/W3s bf16 reorder + wsq ----------------
__global__ __launch_bounds__(256) void prep_kernel(
        const float* __restrict__ W1, const float* __restrict__ W2,
        const float* __restrict__ W3, unsigned short* __restrict__ w2s,
        unsigned short* __restrict__ w3s, float* __restrict__ wsq) {
    int gid = blockIdx.x * 256 + threadIdx.x;   // grid 432 -> 110592 threads
#pragma unroll
    for (int k = 0; k < 2; ++k) {               // W2s: 221184 = (t,kk,co,ci)
        int e = gid * 2 + k;
        int t = e / 73728, r = e % 73728;
        int kk = r / 8192; r %= 8192;
        int co = r / 64, ci = r % 64;
        w2s[e] = f2bf(W2[(size_t)(t * 128 + co) * 576 + ci * 9 + kk]);
    }
#pragma unroll
    for (int k = 0; k < 8; ++k) {               // W3s: 884736
        int e = gid * 8 + k;
        int t = e / 294912, r = e % 294912;
        int kk = r / 32768; r %= 32768;
        int co = r / 128, ci = r % 128;
        w3s[e] = f2bf(W3[(size_t)(t * 256 + co) * 1152 + ci * 9 + kk]);
    }
    if (gid < 1344) {
        int t = gid / 448, r = gid % 448;
        if (r < 64) {
            const float* w = W1 + (size_t)(t * 64 + r) * 25; float s = 0.f;
            for (int k = 0; k < 25; ++k) s += w[k] * w[k];
            wsq[t * 64 + r] = s;
        } else if (r < 192) {
            int c = r - 64;
            const float* w = W2 + (size_t)(t * 128 + c) * 576; float s = 0.f;
            for (int k = 0; k < 576; ++k) { float v = bf2f(f2bf(w[k])); s += v * v; }
            wsq[192 + t * 128 + c] = s;
        } else {
            int c = r - 192;
            const float* w = W3 + (size_t)(t * 256 + c) * 1152; float s = 0.f;
            for (int k = 0; k < 1152; ++k) { float v = bf2f(f2bf(w[k])); s += v * v; }
            wsq[576 + t * 256 + c] = s;
        }
    }
}

// ------------------------- conv1: register-blocked, fuses S2 ---------------
__device__ __forceinline__ void conv1_ch(const float xv[8][8], const float* xsqr,
        const float* wp, float wq, float tw, float itw, float cb,
        const float* apw, float pooled[4]) {
    float acc[16];
#pragma unroll
    for (int i = 0; i < 16; ++i) acc[i] = 0.f;
#pragma unroll
    for (int ky = 0; ky < 5; ++ky)
#pragma unroll
        for (int kx = 0; kx < 5; ++kx) {
            float wv = wp[ky * 5 + kx];
#pragma unroll
            for (int ii = 0; ii < 4; ++ii)
#pragma unroll
                for (int jj = 0; jj < 4; ++jj)
                    acc[ii * 4 + jj] = fmaf(xv[ii + ky][jj + kx], wv, acc[ii * 4 + jj]);
        }
#pragma unroll
    for (int c2 = 0; c2 < 4; ++c2) pooled[c2] = 0.f;
#pragma unroll
    for (int ii = 0; ii < 4; ++ii)
#pragma unroll
        for (int jj = 0; jj < 4; ++jj) {
            float d = fmaf(-2.f, acc[ii * 4 + jj], xsqr[ii * 4 + jj]) + wq;
            d = fminf(fmaxf(d, 0.f), tw);
            float h = 1.f - d * itw;
            h = (h >= cb) ? h : 0.f;
            int pc = (ii >> 1) * 2 + (jj >> 1);
            pooled[pc] = fmaf(h, apw[(ii & 1) * 2 + (jj & 1)], pooled[pc]);
        }
}

// grid (384 images, 4 quarters), block 576 = 36 tiles x 16 ch-groups (4 ch).
// Quarter q owns output rows [12q, 12q+12) -> staged padded rows [12q, 12q+16).
__global__ __launch_bounds__(576) void conv1_kernel(
        const float* __restrict__ x, const float* __restrict__ W1,
        const float* __restrict__ triw, const float* __restrict__ crb,
        const float* __restrict__ alp, const float* __restrict__ wsqb,
        unsigned short* __restrict__ p1u, float* __restrict__ S2) {
    __shared__ float simg[16 * 52];
    __shared__ float srs[16 * 48];
    __shared__ float sxq[12 * 48];
    __shared__ float sw[64 * 25];
    __shared__ float swq[64];
    __shared__ float sS2[144];

    int bi = blockIdx.x;            // image index t*128+b
    int qv = blockIdx.y;            // quarter 0..3
    int t = bi / 128, b = bi % 128;
    int tid = threadIdx.x;
    const float* xim = x + (size_t)(b * 3 + t) * 2304;
    int r0 = 12 * qv;               // first staged padded row

    for (int idx = tid; idx < 16 * 52; idx += 576) {
        int rl = idx / 52, xx = idx % 52 - 2;
        int y = r0 + rl - 2;
        simg[idx] = (y >= 0 && y < 48 && xx >= 0 && xx < 48) ? xim[y * 48 + xx] : 0.f;
    }
    for (int idx = tid; idx < 1600; idx += 576) sw[idx] = W1[(size_t)t * 1600 + idx];
    if (tid < 64) swq[tid] = wsqb[t * 64 + tid];
    if (tid < 144) sS2[tid] = 0.f;
    __syncthreads();

    for (int idx = tid; idx < 16 * 48; idx += 576) {
        int i = idx / 48, ox = idx % 48;
        const float* r = &simg[i * 52 + ox];
        float s = 0.f;
#pragma unroll
        for (int j = 0; j < 5; ++j) s += r[j] * r[j];
        srs[idx] = s;
    }
    __syncthreads();
    {
        int oy = tid / 48, ox = tid % 48;     // exactly 576 entries
        float s = 0.f;
#pragma unroll
        for (int i = 0; i < 5; ++i) s += srs[(oy + i) * 48 + ox];
        sxq[tid] = s;
    }
    __syncthreads();

    int chg = tid / 36, tl = tid % 36;        // 16 groups x 4 channels
    int ty_l = tl / 12, tx = tl % 12;
    int oy0l = ty_l * 4, ox0 = tx * 4;

    float xv[8][8];
#pragma unroll
    for (int r = 0; r < 8; ++r) {
        f32x4 a = *(const f32x4*)&simg[(oy0l + r) * 52 + ox0];
        f32x4 c = *(const f32x4*)&simg[(oy0l + r) * 52 + ox0 + 4];
#pragma unroll
        for (int j = 0; j < 4; ++j) { xv[r][j] = a[j]; xv[r][4 + j] = c[j]; }
    }
    float xsqr[16];
#pragma unroll
    for (int ii = 0; ii < 4; ++ii)
#pragma unroll
        for (int jj = 0; jj < 4; ++jj)
            xsqr[ii * 4 + jj] = sxq[(oy0l + ii) * 48 + ox0 + jj];

    float tw = triw[t * 3 + 0], itw = 1.f / tw;
    float cb = crb[t * 3 + 0];
    float al = alp[t * 2 + 0];
    float apw[4] = {al * al * al * 0.25f, al * al * 0.25f, al * 0.25f, 0.25f};

    unsigned outp[4][2];
    float s2a[4] = {0.f, 0.f, 0.f, 0.f};

#pragma unroll 1
    for (int cp = 0; cp < 2; ++cp) {
        int ch0 = chg * 4 + cp * 2;
        float p0[4], p1[4];
        conv1_ch(xv, xsqr, &sw[ch0 * 25], swq[ch0], tw, itw, cb, apw, p0);
        conv1_ch(xv, xsqr, &sw[(ch0 + 1) * 25], swq[ch0 + 1], tw, itw, cb, apw, p1);
#pragma unroll
        for (int c2 = 0; c2 < 4; ++c2) {
            unsigned short u0 = f2bf(p0[c2]), u1 = f2bf(p1[c2]);
            float v0 = bf2f(u0), v1 = bf2f(u1);
            s2a[c2] += v0 * v0 + v1 * v1;
            outp[c2][cp] = (unsigned)u0 | ((unsigned)u1 << 16);
        }
    }

    size_t imgbase = (size_t)bi * 43264;
#pragma unroll
    for (int c2 = 0; c2 < 4; ++c2) {
        int py_l = 2 * ty_l + (c2 >> 1);                    // 0..5 within quarter
        int py = 6 * qv + py_l, px = tx * 2 + (c2 & 1);
        int cell = (py + 1) * 26 + px + 1;
        uint2* gp = (uint2*)(p1u + imgbase + (size_t)cell * 64 + chg * 4);
        uint2 v; v.x = outp[c2][0]; v.y = outp[c2][1];
        *gp = v;
        atomicAdd(&sS2[py_l * 24 + px], s2a[c2]);
    }
    __syncthreads();
    if (tid < 144)
        S2[(size_t)bi * 576 + (6 * qv + tid / 24) * 24 + tid % 24] = sS2[tid];

    // halo zeros: 100 border cells x 8 uint4 = 800 writes over 4 quarters
    if (tid < 200) {
        int e = qv * 200 + tid;
        int bc = e >> 3, c8 = e & 7;
        int cell;
        if (bc < 26) cell = bc;
        else if (bc < 52) cell = 650 + (bc - 26);
        else { int r = bc - 52; cell = (1 + (r >> 1)) * 26 + ((r & 1) * 25); }
        uint4 z; z.x = 0; z.y = 0; z.z = 0; z.w = 0;
        *(uint4*)(p1u + imgbase + (size_t)cell * 64 + c8 * 8) = z;
    }
}

// ------------------------- s3 (from bf16-rounded values) -------------------
__device__ __forceinline__ float sq8(uint4 u) {
    float s = 0.f;
    const unsigned* p = (const unsigned*)&u;
#pragma unroll
    for (int j = 0; j < 4; ++j) {
        float a = bf2f((unsigned short)(p[j] & 0xFFFFu));
        float b = bf2f((unsigned short)(p[j] >> 16));
        s += a * a + b * b;
    }
    return s;
}

__global__ __launch_bounds__(576) void s3_kernel(const unsigned short* __restrict__ p2u,
                                                 float* __restrict__ S3) {
    int g = blockIdx.x;                 // 0..95
    int tid = threadIdx.x;
    int il = tid / 144, s = tid % 144;
    int i = g * 4 + il;
    int cell = (s / 12 + 1) * 14 + (s % 12) + 1;
    const uint4* gp = (const uint4*)(p2u + ((size_t)i * 196 + cell) * 128);
    float acc = 0.f;
#pragma unroll
    for (int k = 0; k < 16; ++k) acc += sq8(gp[k]);
    S3[(size_t)i * 144 + s] = acc;
}

// ------------------------- conv2: MFMA GEMM + pool -> p2cl -----------------
__global__ __launch_bounds__(576, 3) void conv2_kernel(
        const unsigned short* __restrict__ p1u, const unsigned short* __restrict__ w2s,
        const float* __restrict__ S2, const float* __restrict__ triw,
        const float* __restrict__ crb, const float* __restrict__ alp,
        const float* __restrict__ wsq, unsigned short* __restrict__ p2u) {
    extern __shared__ char sm[];
    float* sS   = (float*)(sm + 124992);
    float* sxq  = (float*)(sm + 127696);
    float* wsqh = (float*)(sm + 130000);
    float* pbuf = (float*)sm;

    int i = blockIdx.x;
    int t = i / 128;
    int co0 = blockIdx.y * 64;
    int tid = threadIdx.x;
    int w = tid >> 6, l = tid & 63;
    int lm = l & 15, q = l >> 4;

    {   // stage image: 676 cells x 64ci bf16 -> rows padded to 72 ushorts
        const uint4* gsrc = (const uint4*)(p1u + (size_t)i * 43264);
        for (int d = tid; d < 5408; d += 576) {
            int cell = d >> 3, c8 = d & 7;
            *(uint4*)(sm + cell * 144 + c8 * 16) = gsrc[(size_t)cell * 8 + c8];
        }
    }
    for (int e = tid; e < 676; e += 576) {
        int yy = e / 26, xx = e % 26;
        sS[e] = (yy >= 1 && yy <= 24 && xx >= 1 && xx <= 24)
                    ? S2[(size_t)i * 576 + (yy - 1) * 24 + (xx - 1)] : 0.f;
    }
    if (tid < 64) wsqh[tid] = wsq[192 + t * 128 + co0 + tid];
    __syncthreads();
    if (tid < 576) {
        int oy = tid / 24, ox = tid % 24;
        float s = 0.f;
#pragma unroll
        for (int ky = 0; ky < 3; ++ky)
#pragma unroll
            for (int kx = 0; kx < 3; ++kx) s += sS[(oy + ky) * 26 + ox + kx];
        sxq[tid] = s;
    }

    int posA[4], oyq[4], oxq[4];
#pragma unroll
    for (int mt = 0; mt < 4; ++mt) {
        int m = w * 64 + mt * 16 + lm;
        posA[mt] = (m / 24) * 26 + (m % 24);
        int sb = w * 64 + mt * 16 + q * 4;
        oyq[mt] = sb / 24; oxq[mt] = sb % 24;
    }

    f32x4 zz; zz[0] = 0.f; zz[1] = 0.f; zz[2] = 0.f; zz[3] = 0.f;
    f32x4 acc[4][4];
#pragma unroll
    for (int a = 0; a < 4; ++a)
#pragma unroll
        for (int bb = 0; bb < 4; ++bb) acc[a][bb] = zz;

    const unsigned short* w2base = w2s + (size_t)t * 9 * 128 * 64;

    for (int kg = 0; kg < 3; ++kg) {
        __syncthreads();
        for (int d = tid; d < 1536; d += 576) {     // 3 kk x 64 co x 64 ci
            int kkl = d / 512, r = d % 512;
            int n = r >> 3, c8 = r & 7;
            const uint4* g = (const uint4*)(w2base + ((size_t)(kg * 3 + kkl) * 128 + co0 + n) * 64);
            *(uint4*)(sm + 97344 + (kkl * 64 + n) * 144 + c8 * 16) = g[c8];
        }
        __syncthreads();
#pragma unroll
        for (int kkl = 0; kkl < 3; ++kkl) {
            int kk = kg * 3 + kkl;
            int kof = (kk / 3) * 26 + (kk % 3);
#pragma unroll
            for (int ks = 0; ks < 2; ++ks) {
                bf16x8 aF[4];
#pragma unroll
                for (int mt = 0; mt < 4; ++mt)
                    aF[mt] = *(const bf16x8*)(sm + (posA[mt] + kof) * 144 + ks * 64 + q * 16);
#pragma unroll
                for (int nt = 0; nt < 4; ++nt) {
                    bf16x8 bF = *(const bf16x8*)(sm + 97344 + (kkl * 64 + nt * 16 + lm) * 144 + ks * 64 + q * 16);
                    acc[0][nt] = __builtin_amdgcn_mfma_f32_16x16x32_bf16(aF[0], bF, acc[0][nt], 0, 0, 0);
                    acc[1][nt] = __builtin_amdgcn_mfma_f32_16x16x32_bf16(aF[1], bF, acc[1][nt], 0, 0, 0);
                    acc[2][nt] = __builtin_amdgcn_mfma_f32_16x16x32_bf16(aF[2], bF, acc[2][nt], 0, 0, 0);
                    acc[3][nt] = __builtin_amdgcn_mfma_f32_16x16x32_bf16(aF[3], bF, acc[3][nt], 0, 0, 0);
                }
            }
        }
    }
    __syncthreads();   // img dead -> pbuf alias

    float tw = triw[t * 3 + 1], itw = 1.f / tw, cb = crb[t * 3 + 1], al = alp[t * 2 + 1];
    float apw[4] = {al * al * al * 0.25f, al * al * 0.25f, al * 0.25f, 0.25f};
#pragma unroll
    for (int mt = 0; mt < 4; ++mt) {
        int sb = w * 64 + mt * 16 + q * 4;
        int cell = oyq[mt] * 12 + (oxq[mt] >> 1);
        int oybit = (oyq[mt] & 1) << 1;
#pragma unroll
        for (int nt = 0; nt < 4; ++nt) {
            int n = nt * 16 + lm;
            float wq = wsqh[n];
            float hw[4];
#pragma unroll
            for (int r = 0; r < 4; ++r) {
                float d = sxq[sb + r] - 2.f * acc[mt][nt][r] + wq;
                d = fminf(fmaxf(d, 0.f), tw);
                float h = 1.f - d * itw;
                h = (h >= cb) ? h : 0.f;
                hw[r] = h * apw[oybit | (r & 1)];
            }
            pbuf[cell * 65 + n] = hw[0] + hw[1];
            pbuf[(cell + 1) * 65 + n] = hw[2] + hw[3];
        }
    }
    __syncthreads();
    for (int e = tid; e < 9216; e += 576) {
        int co_l = e & 63, pp = e >> 6;
        int py = pp / 12, px = pp % 12;
        float v = pbuf[((2 * py) * 12 + px) * 65 + co_l] +
                  pbuf[((2 * py + 1) * 12 + px) * 65 + co_l];
        p2u[((size_t)i * 196 + (py + 1) * 14 + px + 1) * 128 + co0 + co_l] = f2bf(v);
    }
    for (int e = tid; e < 3328; e += 576) {      // 52 border cells x 64 ci
        int co_l = e & 63, bc = e >> 6;
        int cell;
        if (bc < 14) cell = bc;
        else if (bc < 28) cell = 182 + (bc - 14);
        else { int r = bc - 28; cell = (1 + (r >> 1)) * 14 + ((r & 1) * 13); }
        p2u[((size_t)i * 196 + cell) * 128 + co0 + co_l] = 0;
    }
}

// ------------------------- conv3: MFMA GEMM -> h3 bf16 ---------------------
__global__ __launch_bounds__(576, 3) void conv3_kernel(
        const unsigned short* __restrict__ p2u, const unsigned short* __restrict__ w3s,
        const float* __restrict__ S3, const float* __restrict__ triw,
        const float* __restrict__ crb, const float* __restrict__ wsq,
        unsigned short* __restrict__ h3bf) {
    extern __shared__ char sm[];
    float* sxq3  = (float*)(sm + 108800);
    float* wsqh3 = (float*)(sm + 111104);
    float* sS3   = (float*)(sm + 111360);

    int g = blockIdx.x;
    int i0 = g * 4;
    int t = i0 / 128;
    int co0 = blockIdx.y * 64;
    int tid = threadIdx.x;
    int w = tid >> 6, l = tid & 63;
    int lm = l & 15, q = l >> 4;

    for (int e = tid; e < 784; e += 576) {
        int il = e / 196, cell = e % 196;
        int yy = cell / 14, xx = cell % 14;
        sS3[e] = (yy >= 1 && yy <= 12 && xx >= 1 && xx <= 12)
                     ? S3[(size_t)(i0 + il) * 144 + (yy - 1) * 12 + (xx - 1)] : 0.f;
    }
    if (tid < 64) wsqh3[tid] = wsq[576 + t * 256 + co0 + tid];
    __syncthreads();
    if (tid < 576) {
        int il = tid / 144, s = tid % 144;
        int oy = s / 12, ox = s % 12;
        float sum = 0.f;
#pragma unroll
        for (int ky = 0; ky < 3; ++ky)
#pragma unroll
            for (int kx = 0; kx < 3; ++kx)
                sum += sS3[il * 196 + (oy + ky) * 14 + (ox + kx)];
        sxq3[tid] = sum;
    }

    int posA[4], img_l[4], s0a[4];
#pragma unroll
    for (int mt = 0; mt < 4; ++mt) {
        int tb = w * 64 + mt * 16;
        int il = tb / 144, s0 = tb % 144;
        int s = s0 + lm;
        posA[mt] = il * 196 + (s / 12) * 14 + (s % 12);
        img_l[mt] = il; s0a[mt] = s0;
    }

    f32x4 zz; zz[0] = 0.f; zz[1] = 0.f; zz[2] = 0.f; zz[3] = 0.f;
    f32x4 acc[4][4];
#pragma unroll
    for (int a = 0; a < 4; ++a)
#pragma unroll
        for (int bb = 0; bb < 4; ++bb) acc[a][bb] = zz;

    for (int ks = 0; ks < 4; ++ks) {
        __syncthreads();
        for (int d = tid; d < 3136; d += 576) {      // imgS: 4img x 196 x 32ci
            int cg = d >> 2, c4 = d & 3;
            int il = cg / 196, cell = cg % 196;
            const uint4* gp = (const uint4*)(p2u + ((size_t)(i0 + il) * 196 + cell) * 128 + ks * 32);
            *(uint4*)(sm + cg * 80 + c4 * 16) = gp[c4];
        }
        for (int d = tid; d < 2304; d += 576) {      // sbw3: 9kk x 64co x 32ci
            int row = d >> 2, c4 = d & 3;
            int kk = row >> 6, n = row & 63;
            const uint4* gp = (const uint4*)(w3s + ((size_t)(t * 9 + kk) * 256 + co0 + n) * 128 + ks * 32);
            *(uint4*)(sm + 62720 + row * 80 + c4 * 16) = gp[c4];
        }
        __syncthreads();
#pragma unroll 1
        for (int kk = 0; kk < 9; ++kk) {
            int kof = (kk / 3) * 14 + (kk % 3);
            bf16x8 aF[4];
#pragma unroll
            for (int mt = 0; mt < 4; ++mt)
                aF[mt] = *(const bf16x8*)(sm + (posA[mt] + kof) * 80 + q * 16);
#pragma unroll
            for (int nt = 0; nt < 4; ++nt) {
                bf16x8 bF = *(const bf16x8*)(sm + 62720 + (kk * 64 + nt * 16 + lm) * 80 + q * 16);
                acc[0][nt] = __builtin_amdgcn_mfma_f32_16x16x32_bf16(aF[0], bF, acc[0][nt], 0, 0, 0);
                acc[1][nt] = __builtin_amdgcn_mfma_f32_16x16x32_bf16(aF[1], bF, acc[1][nt], 0, 0, 0);
                acc[2][nt] = __builtin_amdgcn_mfma_f32_16x16x32_bf16(aF[2], bF, acc[2][nt], 0, 0, 0);
                acc[3][nt] = __builtin_amdgcn_mfma_f32_16x16x32_bf16(aF[3], bF, acc[3][nt], 0, 0, 0);
            }
        }
    }
    __syncthreads();   // imgS dead -> per-wave transpose tiles

    float tw = triw[t * 3 + 2], itw = 1.f / tw, cb = crb[t * 3 + 2];
    float* tile = (float*)(sm + w * 1280);           // 16 x 20 floats, wave-private
#pragma unroll
    for (int mt = 0; mt < 4; ++mt) {
        int il = img_l[mt], s0 = s0a[mt];
        int bidx = (i0 + il) - t * 128;
        unsigned short* gbase = h3bf + (size_t)bidx * 110592 + (size_t)t * 36864;
#pragma unroll
        for (int nt = 0; nt < 4; ++nt) {
            float wq = wsqh3[nt * 16 + lm];
#pragma unroll
            for (int r = 0; r < 4; ++r) {
                float d = sxq3[il * 144 + s0 + q * 4 + r] - 2.f * acc[mt][nt][r] + wq;
                d = fminf(fmaxf(d, 0.f), tw);
                float h = 1.f - d * itw;
                h = (h >= cb) ? h : 0.f;
                tile[lm * 20 + q * 4 + r] = h;       // [co_l][s_l]
            }
            f32x4 v = *(const f32x4*)(tile + (l >> 2) * 20 + (l & 3) * 4);
            uint2 uv; uv.x = pkbf(v[0], v[1]); uv.y = pkbf(v[2], v[3]);
            *(uint2*)(gbase + (size_t)(co0 + nt * 16 + (l >> 2)) * 144 + s0 + (l & 3) * 4) = uv;
        }
    }
}

// ------------------------- FC: LDS-free bf16 MFMA K-split ------------------
__global__ __launch_bounds__(512) void fc_kernel(
        const unsigned short* __restrict__ h3bf, const float* __restrict__ fcw,
        float* __restrict__ part) {
    int kb = blockIdx.x;
    int f0 = kb * 256;
    int tid = threadIdx.x;
    int w = tid >> 6, l = tid & 63;
    int lm = l & 15, q = l >> 4;

    const unsigned short* abase = h3bf + (size_t)(w * 16 + lm) * 110592 + f0 + q * 8;
    const float* brow[7];
#pragma unroll
    for (int nt = 0; nt < 7; ++nt) {
        int n = nt * 16 + lm;
        if (n > 99) n = 99;
        brow[nt] = fcw + (size_t)n * 110592 + f0 + q * 8;
    }

    f32x4 zz; zz[0] = 0.f; zz[1] = 0.f; zz[2] = 0.f; zz[3] = 0.f;
    f32x4 acc[7];
#pragma unroll
    for (int nt = 0; nt < 7; ++nt) acc[nt] = zz;

#pragma unroll 2
    for (int kc = 0; kc < 8; ++kc) {
        bf16x8 aF = *(const bf16x8*)(abase + kc * 32);
#pragma unroll
        for (int nt = 0; nt < 7; ++nt) {
            f32x4 b0 = *(const f32x4*)(brow[nt] + kc * 32);
            f32x4 b1 = *(const f32x4*)(brow[nt] + kc * 32 + 4);
            union { bf16x8 v; unsigned u[4]; } bF;
            bF.u[0] = pkbf(b0[0], b0[1]);
            bF.u[1] = pkbf(b0[2], b0[3]);
            bF.u[2] = pkbf(b1[0], b1[1]);
            bF.u[3] = pkbf(b1[2], b1[3]);
            acc[nt] = __builtin_amdgcn_mfma_f32_16x16x32_bf16(aF, bF.v, acc[nt], 0, 0, 0);
        }
    }

    float* pb = part + (size_t)kb * 14336;
#pragma unroll
    for (int nt = 0; nt < 7; ++nt)
#pragma unroll
        for (int r = 0; r < 4; ++r)
            pb[(w * 16 + q * 4 + r) * 112 + nt * 16 + lm] = acc[nt][r];
}

// stage 1: sum 54 K-slabs each; grid (8, 50) x 256
__global__ __launch_bounds__(256) void fc_red1_kernel(const float* __restrict__ part,
                                                      float* __restrict__ part2) {
    int c = blockIdx.x;
    int gid = blockIdx.y * 256 + threadIdx.x;
    if (gid >= 12800) return;
    const float* p = part + (size_t)(c * 54) * 14336 + (gid / 100) * 112 + gid % 100;
    float s = 0.f;
#pragma unroll 6
    for (int kb = 0; kb < 54; ++kb) s += p[(size_t)kb * 14336];
    part2[c * 12800 + gid] = s;
}

__global__ __launch_bounds__(256) void fc_red2_kernel(const float* __restrict__ part2,
                                                      const float* __restrict__ fcb,
                                                      float* __restrict__ out) {
    int gid = blockIdx.x * 256 + threadIdx.x;
    if (gid >= 12800) return;
    float s = fcb[gid % 100];
#pragma unroll
    for (int c = 0; c < 8; ++c) s += part2[c * 12800 + gid];
    out[gid] = s;
}

// ---------------------------------------------------------------------------
extern "C" void kernel_launch(void* const* d_in, const int* in_sizes, int n_in,
                              void* d_out, int out_size, void* d_ws, size_t ws_size,
                              hipStream_t stream) {
    const float* x    = (const float*)d_in[0];
    const float* W1   = (const float*)d_in[1];
    const float* W2   = (const float*)d_in[2];
    const float* W3   = (const float*)d_in[3];
    const float* triw = (const float*)d_in[4];
    const float* crb  = (const float*)d_in[5];
    const float* alp  = (const float*)d_in[6];
    const float* fcw  = (const float*)d_in[7];
    const float* fcb  = (const float*)d_in[8];
    float* out = (float*)d_out;
    float* ws  = (float*)d_ws;

    unsigned short* p1u = (unsigned short*)ws;
    unsigned short* p2u = (unsigned short*)(ws + OFF_P2CL);
    float* S2  = ws + OFF_S2;
    float* S3  = ws + OFF_S3;
    float* wsq = ws + OFF_WSQ;
    unsigned short* w2s = (unsigned short*)(ws + OFF_W2S);
    unsigned short* w3s = (unsigned short*)(ws + OFF_W3S);
    float* part  = ws + OFF_PART;
    float* part2 = ws + OFF_PART2;
    unsigned short* h3bf = (unsigned short*)ws;      // aliases p1u (dead by conv3)

    hipFuncSetAttribute((const void*)conv2_kernel,
                        hipFuncAttributeMaxDynamicSharedMemorySize, 130256);
    hipFuncSetAttribute((const void*)conv3_kernel,
                        hipFuncAttributeMaxDynamicSharedMemorySize, 114496);

    prep_kernel<<<dim3(432), dim3(256), 0, stream>>>(W1, W2, W3, w2s, w3s, wsq);
    conv1_kernel<<<dim3(384, 4), dim3(576), 0, stream>>>(x, W1, triw, crb, alp, wsq, p1u, S2);
    conv2_kernel<<<dim3(384, 2), dim3(576), 130256, stream>>>(p1u, w2s, S2, triw, crb, alp, wsq, p2u);
    s3_kernel<<<dim3(96), dim3(576), 0, stream>>>(p2u, S3);
    conv3_kernel<<<dim3(96, 4), dim3(576), 114496, stream>>>(p2u, w3s, S3, triw, crb, wsq, h3bf);
    fc_kernel<<<dim3(432), dim3(512), 0, stream>>>(h3bf, fcw, part);
    fc_red1_kernel<<<dim3(8, 50), dim3(256), 0, stream>>>(part, part2);
    fc_red2_kernel<<<dim3(50), dim3(256), 0, stream>>>(part2, fcb, out);
}

// Round 5
// 398.722 us; speedup vs baseline: 8.8921x; 1.0583x over previous
//
#include <hip/hip_runtime.h>
#include <hip/hip_bf16.h>

// ---------------------------------------------------------------------------
// SFMCNN: conv1 now bf16 MFMA (im2col K=25->32, 4x4-block m-ordering so the
// 2x2 SFM pool is in-register + shfl_xor(16); xsq from im2col rows; S2 via
// lane butterfly). conv2/conv3 bf16 MFMA GEMM, FC LDS-free bf16 MFMA K-split.
//
// ws layout (float offsets):
//   p1u  [0, 8306688)          bf16 (3,128,26,26,64) halo-baked; h3bf aliases
//   p2u  [8306688, +4816896)   bf16 (3,128,14,14,128) halo-baked
//   S2   [13123584, +221184)   fp32 (3*128, 576)
//   S3   [13344768, +55296)
//   wsq  [13400064, +1344)
//   w2s  [13401408, +110592)   bf16 (3,9,128co,64ci)
//   w3s  [13512000, +442368)   bf16 (3,9,256co,128ci)
//   part [13954368, +6193152)  fp32 (432,128,112) FC partials
//   part2[20147520, +102400)   fp32 (8,12800)
// total 20,249,920 floats = 81.0 MB
// ---------------------------------------------------------------------------

static const size_t OFF_P2CL = 8306688;
static const size_t OFF_S2   = 13123584;
static const size_t OFF_S3   = 13344768;
static const size_t OFF_WSQ  = 13400064;
static const size_t OFF_W2S  = 13401408;
static const size_t OFF_W3S  = 13512000;
static const size_t OFF_PART = 13954368;
static const size_t OFF_PART2= 20147520;

typedef short bf16x8 __attribute__((ext_vector_type(8)));
typedef float f32x4 __attribute__((ext_vector_type(4)));

__device__ __forceinline__ unsigned short f2bf(float f) {
    union { float f; unsigned u; } v; v.f = f;
    unsigned r = (v.u + 0x7FFFu + ((v.u >> 16) & 1u)) >> 16;
    return (unsigned short)r;
}
__device__ __forceinline__ float bf2f(unsigned short h) {
    union { unsigned u; float f; } v; v.u = ((unsigned)h) << 16;
    return v.f;
}
__device__ __forceinline__ unsigned pkbf(float a, float b) {
    union { __hip_bfloat162 h2; unsigned u; } c;
    c.h2 = __float22bfloat162_rn(make_float2(a, b));
    return c.u;
}

// ------------------------- prep: W2s/W3s bf16 reorder + wsq ----------------
__global__ __launch_bounds__(256) void prep_kernel(
        const float* __restrict__ W1, const float* __restrict__ W2,
        const float* __restrict__ W3, unsigned short* __restrict__ w2s,
        unsigned short* __restrict__ w3s, float* __restrict__ wsq) {
    int gid = blockIdx.x * 256 + threadIdx.x;   // grid 432 -> 110592 threads
#pragma unroll
    for (int k = 0; k < 2; ++k) {               // W2s: 221184 = (t,kk,co,ci)
        int e = gid * 2 + k;
        int t = e / 73728, r = e % 73728;
        int kk = r / 8192; r %= 8192;
        int co = r / 64, ci = r % 64;
        w2s[e] = f2bf(W2[(size_t)(t * 128 + co) * 576 + ci * 9 + kk]);
    }
#pragma unroll
    for (int k = 0; k < 8; ++k) {               // W3s: 884736
        int e = gid * 8 + k;
        int t = e / 294912, r = e % 294912;
        int kk = r / 32768; r %= 32768;
        int co = r / 128, ci = r % 128;
        w3s[e] = f2bf(W3[(size_t)(t * 256 + co) * 1152 + ci * 9 + kk]);
    }
    if (gid < 1152) {
        int t = gid / 384, r = gid % 384;
        if (r < 128) {
            const float* w = W2 + (size_t)(t * 128 + r) * 576; float s = 0.f;
            for (int k = 0; k < 576; ++k) { float v = bf2f(f2bf(w[k])); s += v * v; }
            wsq[192 + t * 128 + r] = s;
        } else {
            int c = r - 128;
            const float* w = W3 + (size_t)(t * 256 + c) * 1152; float s = 0.f;
            for (int k = 0; k < 1152; ++k) { float v = bf2f(f2bf(w[k])); s += v * v; }
            wsq[576 + t * 256 + c] = s;
        }
    }
}

// ------------------------- conv1: MFMA im2col, fused pool + S2 -------------
// grid (384 images, 4 quarters), block 576 = 9 waves.
// Quarter qv owns output rows [12qv, 12qv+12): M=576 (36 tiles of 4x4 spatial
// blocks), N=64 channels, K=32 (25 taps padded). C layout: m=q*4+r, n=lm;
// within-tile m-ordering idx=yy*4+xx so q=yy, r=xx -> pool = pair-add(r) +
// shfl_xor(16) (q). S2 = in-lane nt-sum then lm-butterfly.
__global__ __launch_bounds__(576) void conv1_kernel(
        const float* __restrict__ x, const float* __restrict__ W1,
        const float* __restrict__ triw, const float* __restrict__ crb,
        const float* __restrict__ alp,
        unsigned short* __restrict__ p1u, float* __restrict__ S2) {
    __shared__ unsigned short simgbf[16 * 56];   // bf16 x strip, rows r0-2..r0+13
    __shared__ unsigned short sA[576 * 40];      // im2col, rows padded to 40
    __shared__ unsigned short sB[64 * 40];       // weights bf16, k-major
    __shared__ float sxq[576];
    __shared__ float swq[64];

    int bi = blockIdx.x;            // image index t*128+b
    int qv = blockIdx.y;            // quarter 0..3
    int t = bi / 128, b = bi % 128;
    int tid = threadIdx.x;
    const float* xim = x + (size_t)(b * 3 + t) * 2304;
    int r0 = 12 * qv;

    for (int idx = tid; idx < 16 * 52; idx += 576) {
        int rl = idx / 52, cc = idx % 52;
        int y = r0 + rl - 2, xx = cc - 2;
        float v = (y >= 0 && y < 48 && xx >= 0 && xx < 48) ? xim[y * 48 + xx] : 0.f;
        simgbf[rl * 56 + cc] = f2bf(v);
    }
    if (tid < 64) {
        const float* wp = W1 + (size_t)t * 1600 + tid * 25;
        unsigned rw[20];
        float s = 0.f;
        unsigned short tmp[40];
#pragma unroll
        for (int k = 0; k < 25; ++k) {
            unsigned short u = f2bf(wp[k]);
            tmp[k] = u; float v = bf2f(u); s += v * v;
        }
#pragma unroll
        for (int k = 25; k < 40; ++k) tmp[k] = 0;
#pragma unroll
        for (int j = 0; j < 20; ++j) rw[j] = (unsigned)tmp[2 * j] | ((unsigned)tmp[2 * j + 1] << 16);
        uint4* bp = (uint4*)&sB[tid * 40];
#pragma unroll
        for (int j = 0; j < 5; ++j) {
            uint4 v4; v4.x = rw[4 * j]; v4.y = rw[4 * j + 1]; v4.z = rw[4 * j + 2]; v4.w = rw[4 * j + 3];
            bp[j] = v4;
        }
        swq[tid] = s;
    }
    __syncthreads();

    {   // im2col row tid (+ xsq)
        int tile = tid >> 4, idx = tid & 15;
        int by = tile / 12, bx = tile % 12;
        int yy = idx >> 2, xx2 = idx & 3;
        int oy = by * 4 + yy, ox = bx * 4 + xx2;     // local 0..11 / 0..47
        unsigned short row[40];
        float s = 0.f;
#pragma unroll
        for (int ky = 0; ky < 5; ++ky)
#pragma unroll
            for (int kx = 0; kx < 5; ++kx) {
                unsigned short u = simgbf[(oy + ky) * 56 + ox + kx];
                row[ky * 5 + kx] = u; float v = bf2f(u); s += v * v;
            }
#pragma unroll
        for (int k = 25; k < 40; ++k) row[k] = 0;
        unsigned rw[20];
#pragma unroll
        for (int j = 0; j < 20; ++j) rw[j] = (unsigned)row[2 * j] | ((unsigned)row[2 * j + 1] << 16);
        uint4* ap = (uint4*)&sA[tid * 40];
#pragma unroll
        for (int j = 0; j < 5; ++j) {
            uint4 v4; v4.x = rw[4 * j]; v4.y = rw[4 * j + 1]; v4.z = rw[4 * j + 2]; v4.w = rw[4 * j + 3];
            ap[j] = v4;
        }
        sxq[tid] = s;
    }
    __syncthreads();

    int w = tid >> 6, l = tid & 63;
    int lm = l & 15, q = l >> 4;

    f32x4 zz; zz[0] = 0.f; zz[1] = 0.f; zz[2] = 0.f; zz[3] = 0.f;
    f32x4 acc[4][4];
    bf16x8 aF[4], bF[4];
#pragma unroll
    for (int mt = 0; mt < 4; ++mt)
        aF[mt] = *(const bf16x8*)(&sA[((w * 4 + mt) * 16 + lm) * 40 + q * 8]);
#pragma unroll
    for (int nt = 0; nt < 4; ++nt)
        bF[nt] = *(const bf16x8*)(&sB[(nt * 16 + lm) * 40 + q * 8]);
#pragma unroll
    for (int mt = 0; mt < 4; ++mt)
#pragma unroll
        for (int nt = 0; nt < 4; ++nt)
            acc[mt][nt] = __builtin_amdgcn_mfma_f32_16x16x32_bf16(aF[mt], bF[nt], zz, 0, 0, 0);

    float wqv[4];
#pragma unroll
    for (int nt = 0; nt < 4; ++nt) wqv[nt] = swq[nt * 16 + lm];

    float tw = triw[t * 3 + 0], itw = 1.f / tw;
    float cb = crb[t * 3 + 0];
    float al = alp[t * 2 + 0];
    float apw[4] = {al * al * al * 0.25f, al * al * 0.25f, al * 0.25f, 0.25f};
    int qa = q & 1;
    size_t imgbase = (size_t)bi * 43264;

#pragma unroll
    for (int mt = 0; mt < 4; ++mt) {
        int tile = w * 4 + mt;
        int by = tile / 12, bx = tile % 12;
        f32x4 xq = *(const f32x4*)&sxq[tile * 16 + q * 4];
        float s2loc[2] = {0.f, 0.f};
        int py_g = qv * 6 + by * 2 + (q >> 1);
        int cell0 = (py_g + 1) * 26 + (bx * 2 + 1);
        float pv[4][2];
#pragma unroll
        for (int nt = 0; nt < 4; ++nt) {
            float hw[4];
#pragma unroll
            for (int r = 0; r < 4; ++r) {
                float d = fmaf(-2.f, acc[mt][nt][r], xq[r]) + wqv[nt];
                d = fminf(fmaxf(d, 0.f), tw);
                float h = 1.f - d * itw;
                h = (h >= cb) ? h : 0.f;
                hw[r] = h * apw[qa * 2 + (r & 1)];
            }
            float ph0 = hw[0] + hw[1], ph1 = hw[2] + hw[3];
            float p0 = ph0 + __shfl_xor(ph0, 16, 64);
            float p1 = ph1 + __shfl_xor(ph1, 16, 64);
            unsigned short u0 = f2bf(p0), u1 = f2bf(p1);
            float v0 = bf2f(u0), v1 = bf2f(u1);
            s2loc[0] += v0 * v0;
            s2loc[1] += v1 * v1;
            pv[nt][0] = p0; pv[nt][1] = p1;
        }
        // butterfly over lm (16-lane group) for S2
#pragma unroll
        for (int m2 = 1; m2 < 16; m2 <<= 1) {
            s2loc[0] += __shfl_xor(s2loc[0], m2, 64);
            s2loc[1] += __shfl_xor(s2loc[1], m2, 64);
        }
        if ((q & 1) == 0) {
#pragma unroll
            for (int nt = 0; nt < 4; ++nt) {
                p1u[imgbase + (size_t)cell0 * 64 + nt * 16 + lm] = f2bf(pv[nt][0]);
                p1u[imgbase + (size_t)(cell0 + 1) * 64 + nt * 16 + lm] = f2bf(pv[nt][1]);
            }
            if (lm == 0) {
                S2[(size_t)bi * 576 + py_g * 24 + bx * 2] = s2loc[0];
                S2[(size_t)bi * 576 + py_g * 24 + bx * 2 + 1] = s2loc[1];
            }
        }
    }

    // halo zeros: 100 border cells x 8 uint4 = 800 writes over 4 quarters
    if (tid < 200) {
        int e = qv * 200 + tid;
        int bc = e >> 3, c8 = e & 7;
        int cell;
        if (bc < 26) cell = bc;
        else if (bc < 52) cell = 650 + (bc - 26);
        else { int r = bc - 52; cell = (1 + (r >> 1)) * 26 + ((r & 1) * 25); }
        uint4 z; z.x = 0; z.y = 0; z.z = 0; z.w = 0;
        *(uint4*)(p1u + imgbase + (size_t)cell * 64 + c8 * 8) = z;
    }
}

// ------------------------- s3 (from bf16-rounded values) -------------------
__device__ __forceinline__ float sq8(uint4 u) {
    float s = 0.f;
    const unsigned* p = (const unsigned*)&u;
#pragma unroll
    for (int j = 0; j < 4; ++j) {
        float a = bf2f((unsigned short)(p[j] & 0xFFFFu));
        float b = bf2f((unsigned short)(p[j] >> 16));
        s += a * a + b * b;
    }
    return s;
}

__global__ __launch_bounds__(576) void s3_kernel(const unsigned short* __restrict__ p2u,
                                                 float* __restrict__ S3) {
    int g = blockIdx.x;                 // 0..95
    int tid = threadIdx.x;
    int il = tid / 144, s = tid % 144;
    int i = g * 4 + il;
    int cell = (s / 12 + 1) * 14 + (s % 12) + 1;
    const uint4* gp = (const uint4*)(p2u + ((size_t)i * 196 + cell) * 128);
    float acc = 0.f;
#pragma unroll
    for (int k = 0; k < 16; ++k) acc += sq8(gp[k]);
    S3[(size_t)i * 144 + s] = acc;
}

// ------------------------- conv2: MFMA GEMM + pool -> p2cl -----------------
__global__ __launch_bounds__(576, 3) void conv2_kernel(
        const unsigned short* __restrict__ p1u, const unsigned short* __restrict__ w2s,
        const float* __restrict__ S2, const float* __restrict__ triw,
        const float* __restrict__ crb, const float* __restrict__ alp,
        const float* __restrict__ wsq, unsigned short* __restrict__ p2u) {
    extern __shared__ char sm[];
    float* sS   = (float*)(sm + 124992);
    float* sxq  = (float*)(sm + 127696);
    float* wsqh = (float*)(sm + 130000);
    float* pbuf = (float*)sm;

    int i = blockIdx.x;
    int t = i / 128;
    int co0 = blockIdx.y * 64;
    int tid = threadIdx.x;
    int w = tid >> 6, l = tid & 63;
    int lm = l & 15, q = l >> 4;

    {   // stage image: 676 cells x 64ci bf16 -> rows padded to 72 ushorts
        const uint4* gsrc = (const uint4*)(p1u + (size_t)i * 43264);
        for (int d = tid; d < 5408; d += 576) {
            int cell = d >> 3, c8 = d & 7;
            *(uint4*)(sm + cell * 144 + c8 * 16) = gsrc[(size_t)cell * 8 + c8];
        }
    }
    for (int e = tid; e < 676; e += 576) {
        int yy = e / 26, xx = e % 26;
        sS[e] = (yy >= 1 && yy <= 24 && xx >= 1 && xx <= 24)
                    ? S2[(size_t)i * 576 + (yy - 1) * 24 + (xx - 1)] : 0.f;
    }
    if (tid < 64) wsqh[tid] = wsq[192 + t * 128 + co0 + tid];
    __syncthreads();
    if (tid < 576) {
        int oy = tid / 24, ox = tid % 24;
        float s = 0.f;
#pragma unroll
        for (int ky = 0; ky < 3; ++ky)
#pragma unroll
            for (int kx = 0; kx < 3; ++kx) s += sS[(oy + ky) * 26 + ox + kx];
        sxq[tid] = s;
    }

    int posA[4], oyq[4], oxq[4];
#pragma unroll
    for (int mt = 0; mt < 4; ++mt) {
        int m = w * 64 + mt * 16 + lm;
        posA[mt] = (m / 24) * 26 + (m % 24);
        int sb = w * 64 + mt * 16 + q * 4;
        oyq[mt] = sb / 24; oxq[mt] = sb % 24;
    }

    f32x4 zz; zz[0] = 0.f; zz[1] = 0.f; zz[2] = 0.f; zz[3] = 0.f;
    f32x4 acc[4][4];
#pragma unroll
    for (int a = 0; a < 4; ++a)
#pragma unroll
        for (int bb = 0; bb < 4; ++bb) acc[a][bb] = zz;

    const unsigned short* w2base = w2s + (size_t)t * 9 * 128 * 64;

    for (int kg = 0; kg < 3; ++kg) {
        __syncthreads();
        for (int d = tid; d < 1536; d += 576) {     // 3 kk x 64 co x 64 ci
            int kkl = d / 512, r = d % 512;
            int n = r >> 3, c8 = r & 7;
            const uint4* g = (const uint4*)(w2base + ((size_t)(kg * 3 + kkl) * 128 + co0 + n) * 64);
            *(uint4*)(sm + 97344 + (kkl * 64 + n) * 144 + c8 * 16) = g[c8];
        }
        __syncthreads();
#pragma unroll
        for (int kkl = 0; kkl < 3; ++kkl) {
            int kk = kg * 3 + kkl;
            int kof = (kk / 3) * 26 + (kk % 3);
#pragma unroll
            for (int ks = 0; ks < 2; ++ks) {
                bf16x8 aF[4];
#pragma unroll
                for (int mt = 0; mt < 4; ++mt)
                    aF[mt] = *(const bf16x8*)(sm + (posA[mt] + kof) * 144 + ks * 64 + q * 16);
#pragma unroll
                for (int nt = 0; nt < 4; ++nt) {
                    bf16x8 bF = *(const bf16x8*)(sm + 97344 + (kkl * 64 + nt * 16 + lm) * 144 + ks * 64 + q * 16);
                    acc[0][nt] = __builtin_amdgcn_mfma_f32_16x16x32_bf16(aF[0], bF, acc[0][nt], 0, 0, 0);
                    acc[1][nt] = __builtin_amdgcn_mfma_f32_16x16x32_bf16(aF[1], bF, acc[1][nt], 0, 0, 0);
                    acc[2][nt] = __builtin_amdgcn_mfma_f32_16x16x32_bf16(aF[2], bF, acc[2][nt], 0, 0, 0);
                    acc[3][nt] = __builtin_amdgcn_mfma_f32_16x16x32_bf16(aF[3], bF, acc[3][nt], 0, 0, 0);
                }
            }
        }
    }
    __syncthreads();   // img dead -> pbuf alias

    float tw = triw[t * 3 + 1], itw = 1.f / tw, cb = crb[t * 3 + 1], al = alp[t * 2 + 1];
    float apw[4] = {al * al * al * 0.25f, al * al * 0.25f, al * 0.25f, 0.25f};
#pragma unroll
    for (int mt = 0; mt < 4; ++mt) {
        int sb = w * 64 + mt * 16 + q * 4;
        int cell = oyq[mt] * 12 + (oxq[mt] >> 1);
        int oybit = (oyq[mt] & 1) << 1;
#pragma unroll
        for (int nt = 0; nt < 4; ++nt) {
            int n = nt * 16 + lm;
            float wq = wsqh[n];
            float hw[4];
#pragma unroll
            for (int r = 0; r < 4; ++r) {
                float d = sxq[sb + r] - 2.f * acc[mt][nt][r] + wq;
                d = fminf(fmaxf(d, 0.f), tw);
                float h = 1.f - d * itw;
                h = (h >= cb) ? h : 0.f;
                hw[r] = h * apw[oybit | (r & 1)];
            }
            pbuf[cell * 65 + n] = hw[0] + hw[1];
            pbuf[(cell + 1) * 65 + n] = hw[2] + hw[3];
        }
    }
    __syncthreads();
    for (int e = tid; e < 9216; e += 576) {
        int co_l = e & 63, pp = e >> 6;
        int py = pp / 12, px = pp % 12;
        float v = pbuf[((2 * py) * 12 + px) * 65 + co_l] +
                  pbuf[((2 * py + 1) * 12 + px) * 65 + co_l];
        p2u[((size_t)i * 196 + (py + 1) * 14 + px + 1) * 128 + co0 + co_l] = f2bf(v);
    }
    for (int e = tid; e < 3328; e += 576) {      // 52 border cells x 64 ci
        int co_l = e & 63, bc = e >> 6;
        int cell;
        if (bc < 14) cell = bc;
        else if (bc < 28) cell = 182 + (bc - 14);
        else { int r = bc - 28; cell = (1 + (r >> 1)) * 14 + ((r & 1) * 13); }
        p2u[((size_t)i * 196 + cell) * 128 + co0 + co_l] = 0;
    }
}

// ------------------------- conv3: MFMA GEMM -> h3 bf16 ---------------------
__global__ __launch_bounds__(576, 3) void conv3_kernel(
        const unsigned short* __restrict__ p2u, const unsigned short* __restrict__ w3s,
        const float* __restrict__ S3, const float* __restrict__ triw,
        const float* __restrict__ crb, const float* __restrict__ wsq,
        unsigned short* __restrict__ h3bf) {
    extern __shared__ char sm[];
    float* sxq3  = (float*)(sm + 108800);
    float* wsqh3 = (float*)(sm + 111104);
    float* sS3   = (float*)(sm + 111360);

    int g = blockIdx.x;
    int i0 = g * 4;
    int t = i0 / 128;
    int co0 = blockIdx.y * 64;
    int tid = threadIdx.x;
    int w = tid >> 6, l = tid & 63;
    int lm = l & 15, q = l >> 4;

    for (int e = tid; e < 784; e += 576) {
        int il = e / 196, cell = e % 196;
        int yy = cell / 14, xx = cell % 14;
        sS3[e] = (yy >= 1 && yy <= 12 && xx >= 1 && xx <= 12)
                     ? S3[(size_t)(i0 + il) * 144 + (yy - 1) * 12 + (xx - 1)] : 0.f;
    }
    if (tid < 64) wsqh3[tid] = wsq[576 + t * 256 + co0 + tid];
    __syncthreads();
    if (tid < 576) {
        int il = tid / 144, s = tid % 144;
        int oy = s / 12, ox = s % 12;
        float sum = 0.f;
#pragma unroll
        for (int ky = 0; ky < 3; ++ky)
#pragma unroll
            for (int kx = 0; kx < 3; ++kx)
                sum += sS3[il * 196 + (oy + ky) * 14 + (ox + kx)];
        sxq3[tid] = sum;
    }

    int posA[4], img_l[4], s0a[4];
#pragma unroll
    for (int mt = 0; mt < 4; ++mt) {
        int tb = w * 64 + mt * 16;
        int il = tb / 144, s0 = tb % 144;
        int s = s0 + lm;
        posA[mt] = il * 196 + (s / 12) * 14 + (s % 12);
        img_l[mt] = il; s0a[mt] = s0;
    }

    f32x4 zz; zz[0] = 0.f; zz[1] = 0.f; zz[2] = 0.f; zz[3] = 0.f;
    f32x4 acc[4][4];
#pragma unroll
    for (int a = 0; a < 4; ++a)
#pragma unroll
        for (int bb = 0; bb < 4; ++bb) acc[a][bb] = zz;

    for (int ks = 0; ks < 4; ++ks) {
        __syncthreads();
        for (int d = tid; d < 3136; d += 576) {      // imgS: 4img x 196 x 32ci
            int cg = d >> 2, c4 = d & 3;
            int il = cg / 196, cell = cg % 196;
            const uint4* gp = (const uint4*)(p2u + ((size_t)(i0 + il) * 196 + cell) * 128 + ks * 32);
            *(uint4*)(sm + cg * 80 + c4 * 16) = gp[c4];
        }
        for (int d = tid; d < 2304; d += 576) {      // sbw3: 9kk x 64co x 32ci
            int row = d >> 2, c4 = d & 3;
            int kk = row >> 6, n = row & 63;
            const uint4* gp = (const uint4*)(w3s + ((size_t)(t * 9 + kk) * 256 + co0 + n) * 128 + ks * 32);
            *(uint4*)(sm + 62720 + row * 80 + c4 * 16) = gp[c4];
        }
        __syncthreads();
#pragma unroll 1
        for (int kk = 0; kk < 9; ++kk) {
            int kof = (kk / 3) * 14 + (kk % 3);
            bf16x8 aF[4];
#pragma unroll
            for (int mt = 0; mt < 4; ++mt)
                aF[mt] = *(const bf16x8*)(sm + (posA[mt] + kof) * 80 + q * 16);
#pragma unroll
            for (int nt = 0; nt < 4; ++nt) {
                bf16x8 bF = *(const bf16x8*)(sm + 62720 + (kk * 64 + nt * 16 + lm) * 80 + q * 16);
                acc[0][nt] = __builtin_amdgcn_mfma_f32_16x16x32_bf16(aF[0], bF, acc[0][nt], 0, 0, 0);
                acc[1][nt] = __builtin_amdgcn_mfma_f32_16x16x32_bf16(aF[1], bF, acc[1][nt], 0, 0, 0);
                acc[2][nt] = __builtin_amdgcn_mfma_f32_16x16x32_bf16(aF[2], bF, acc[2][nt], 0, 0, 0);
                acc[3][nt] = __builtin_amdgcn_mfma_f32_16x16x32_bf16(aF[3], bF, acc[3][nt], 0, 0, 0);
            }
        }
    }
    __syncthreads();   // imgS dead -> per-wave transpose tiles

    float tw = triw[t * 3 + 2], itw = 1.f / tw, cb = crb[t * 3 + 2];
    float* tile = (float*)(sm + w * 1280);           // 16 x 20 floats, wave-private
#pragma unroll
    for (int mt = 0; mt < 4; ++mt) {
        int il = img_l[mt], s0 = s0a[mt];
        int bidx = (i0 + il) - t * 128;
        unsigned short* gbase = h3bf + (size_t)bidx * 110592 + (size_t)t * 36864;
#pragma unroll
        for (int nt = 0; nt < 4; ++nt) {
            float wq = wsqh3[nt * 16 + lm];
#pragma unroll
            for (int r = 0; r < 4; ++r) {
                float d = sxq3[il * 144 + s0 + q * 4 + r] - 2.f * acc[mt][nt][r] + wq;
                d = fminf(fmaxf(d, 0.f), tw);
                float h = 1.f - d * itw;
                h = (h >= cb) ? h : 0.f;
                tile[lm * 20 + q * 4 + r] = h;       // [co_l][s_l]
            }
            f32x4 v = *(const f32x4*)(tile + (l >> 2) * 20 + (l & 3) * 4);
            uint2 uv; uv.x = pkbf(v[0], v[1]); uv.y = pkbf(v[2], v[3]);
            *(uint2*)(gbase + (size_t)(co0 + nt * 16 + (l >> 2)) * 144 + s0 + (l & 3) * 4) = uv;
        }
    }
}

// ------------------------- FC: LDS-free bf16 MFMA K-split ------------------
__global__ __launch_bounds__(512) void fc_kernel(
        const unsigned short* __restrict__ h3bf, const float* __restrict__ fcw,
        float* __restrict__ part) {
    int kb = blockIdx.x;
    int f0 = kb * 256;
    int tid = threadIdx.x;
    int w = tid >> 6, l = tid & 63;
    int lm = l & 15, q = l >> 4;

    const unsigned short* abase = h3bf + (size_t)(w * 16 + lm) * 110592 + f0 + q * 8;
    const float* brow[7];
#pragma unroll
    for (int nt = 0; nt < 7; ++nt) {
        int n = nt * 16 + lm;
        if (n > 99) n = 99;
        brow[nt] = fcw + (size_t)n * 110592 + f0 + q * 8;
    }

    f32x4 zz; zz[0] = 0.f; zz[1] = 0.f; zz[2] = 0.f; zz[3] = 0.f;
    f32x4 acc[7];
#pragma unroll
    for (int nt = 0; nt < 7; ++nt) acc[nt] = zz;

#pragma unroll 2
    for (int kc = 0; kc < 8; ++kc) {
        bf16x8 aF = *(const bf16x8*)(abase + kc * 32);
#pragma unroll
        for (int nt = 0; nt < 7; ++nt) {
            f32x4 b0 = *(const f32x4*)(brow[nt] + kc * 32);
            f32x4 b1 = *(const f32x4*)(brow[nt] + kc * 32 + 4);
            union { bf16x8 v; unsigned u[4]; } bF;
            bF.u[0] = pkbf(b0[0], b0[1]);
            bF.u[1] = pkbf(b0[2], b0[3]);
            bF.u[2] = pkbf(b1[0], b1[1]);
            bF.u[3] = pkbf(b1[2], b1[3]);
            acc[nt] = __builtin_amdgcn_mfma_f32_16x16x32_bf16(aF, bF.v, acc[nt], 0, 0, 0);
        }
    }

    float* pb = part + (size_t)kb * 14336;
#pragma unroll
    for (int nt = 0; nt < 7; ++nt)
#pragma unroll
        for (int r = 0; r < 4; ++r)
            pb[(w * 16 + q * 4 + r) * 112 + nt * 16 + lm] = acc[nt][r];
}

// stage 1: sum 54 K-slabs each; grid (8, 50) x 256
__global__ __launch_bounds__(256) void fc_red1_kernel(const float* __restrict__ part,
                                                      float* __restrict__ part2) {
    int c = blockIdx.x;
    int gid = blockIdx.y * 256 + threadIdx.x;
    if (gid >= 12800) return;
    const float* p = part + (size_t)(c * 54) * 14336 + (gid / 100) * 112 + gid % 100;
    float s = 0.f;
#pragma unroll 6
    for (int kb = 0; kb < 54; ++kb) s += p[(size_t)kb * 14336];
    part2[c * 12800 + gid] = s;
}

__global__ __launch_bounds__(256) void fc_red2_kernel(const float* __restrict__ part2,
                                                      const float* __restrict__ fcb,
                                                      float* __restrict__ out) {
    int gid = blockIdx.x * 256 + threadIdx.x;
    if (gid >= 12800) return;
    float s = fcb[gid % 100];
#pragma unroll
    for (int c = 0; c < 8; ++c) s += part2[c * 12800 + gid];
    out[gid] = s;
}

// ---------------------------------------------------------------------------
extern "C" void kernel_launch(void* const* d_in, const int* in_sizes, int n_in,
                              void* d_out, int out_size, void* d_ws, size_t ws_size,
                              hipStream_t stream) {
    const float* x    = (const float*)d_in[0];
    const float* W1   = (const float*)d_in[1];
    const float* W2   = (const float*)d_in[2];
    const float* W3   = (const float*)d_in[3];
    const float* triw = (const float*)d_in[4];
    const float* crb  = (const float*)d_in[5];
    const float* alp  = (const float*)d_in[6];
    const float* fcw  = (const float*)d_in[7];
    const float* fcb  = (const float*)d_in[8];
    float* out = (float*)d_out;
    float* ws  = (float*)d_ws;

    unsigned short* p1u = (unsigned short*)ws;
    unsigned short* p2u = (unsigned short*)(ws + OFF_P2CL);
    float* S2  = ws + OFF_S2;
    float* S3  = ws + OFF_S3;
    float* wsq = ws + OFF_WSQ;
    unsigned short* w2s = (unsigned short*)(ws + OFF_W2S);
    unsigned short* w3s = (unsigned short*)(ws + OFF_W3S);
    float* part  = ws + OFF_PART;
    float* part2 = ws + OFF_PART2;
    unsigned short* h3bf = (unsigned short*)ws;      // aliases p1u (dead by conv3)

    hipFuncSetAttribute((const void*)conv2_kernel,
                        hipFuncAttributeMaxDynamicSharedMemorySize, 130256);
    hipFuncSetAttribute((const void*)conv3_kernel,
                        hipFuncAttributeMaxDynamicSharedMemorySize, 114496);

    prep_kernel<<<dim3(432), dim3(256), 0, stream>>>(W1, W2, W3, w2s, w3s, wsq);
    conv1_kernel<<<dim3(384, 4), dim3(576), 0, stream>>>(x, W1, triw, crb, alp, p1u, S2);
    conv2_kernel<<<dim3(384, 2), dim3(576), 130256, stream>>>(p1u, w2s, S2, triw, crb, alp, wsq, p2u);
    s3_kernel<<<dim3(96), dim3(576), 0, stream>>>(p2u, S3);
    conv3_kernel<<<dim3(96, 4), dim3(576), 114496, stream>>>(p2u, w3s, S3, triw, crb, wsq, h3bf);
    fc_kernel<<<dim3(432), dim3(512), 0, stream>>>(h3bf, fcw, part);
    fc_red1_kernel<<<dim3(8, 50), dim3(256), 0, stream>>>(part, part2);
    fc_red2_kernel<<<dim3(50), dim3(256), 0, stream>>>(part2, fcb, out);
}

// Round 6
// 373.568 us; speedup vs baseline: 9.4909x; 1.0673x over previous
//
#include <hip/hip_runtime.h>
#include <hip/hip_bf16.h>

// ---------------------------------------------------------------------------
// SFMCNN: conv1 MFMA im2col; conv2/conv3 rewritten: 2-blocks/CU (LDS ~67KB),
// exact grids (6/CU and 3/CU), global_load_lds(16B) async staging into a
// XOR-swizzled pad-free LDS layout (conflict-free b128 fragment reads),
// conv2 fuses pool + S3 (s3_kernel eliminated). FC LDS-free bf16 MFMA K-split.
//
// ws layout (float offsets): unchanged from round 5.
//   p1u  [0, 8306688)          bf16 (3,128,26,26,64) halo-baked; h3bf aliases
//   p2u  [8306688, +4816896)   bf16 (3,128,14,14,128) halo-baked
//   S2   [13123584, +221184)   S3 [13344768, +55296)  wsq [13400064, +1344)
//   w2s  [13401408, +110592)   w3s [13512000, +442368)
//   part [13954368, +6193152)  part2 [20147520, +102400)
// ---------------------------------------------------------------------------

static const size_t OFF_P2CL = 8306688;
static const size_t OFF_S2   = 13123584;
static const size_t OFF_S3   = 13344768;
static const size_t OFF_WSQ  = 13400064;
static const size_t OFF_W2S  = 13401408;
static const size_t OFF_W3S  = 13512000;
static const size_t OFF_PART = 13954368;
static const size_t OFF_PART2= 20147520;

typedef short bf16x8 __attribute__((ext_vector_type(8)));
typedef float f32x4 __attribute__((ext_vector_type(4)));

__device__ __forceinline__ unsigned short f2bf(float f) {
    union { float f; unsigned u; } v; v.f = f;
    unsigned r = (v.u + 0x7FFFu + ((v.u >> 16) & 1u)) >> 16;
    return (unsigned short)r;
}
__device__ __forceinline__ float bf2f(unsigned short h) {
    union { unsigned u; float f; } v; v.u = ((unsigned)h) << 16;
    return v.f;
}
__device__ __forceinline__ unsigned pkbf(float a, float b) {
    union { __hip_bfloat162 h2; unsigned u; } c;
    c.h2 = __float22bfloat162_rn(make_float2(a, b));
    return c.u;
}
// async 16B/lane global->LDS; lds must be wave-uniform base (lane*16 implicit)
__device__ __forceinline__ void async16(void* lds, const void* g) {
    __builtin_amdgcn_global_load_lds(
        (const __attribute__((address_space(1))) unsigned*)g,
        (__attribute__((address_space(3))) unsigned*)lds, 16, 0, 0);
}

// ------------------------- prep: reorders + wsq + S3 zero ------------------
__global__ __launch_bounds__(256) void prep_kernel(
        const float* __restrict__ W2, const float* __restrict__ W3,
        unsigned short* __restrict__ w2s, unsigned short* __restrict__ w3s,
        float* __restrict__ wsq, float* __restrict__ S3) {
    int gid = blockIdx.x * 256 + threadIdx.x;   // grid 432 -> 110592 threads
#pragma unroll
    for (int k = 0; k < 2; ++k) {               // W2s: (t,kk,co128,ci64)
        int e = gid * 2 + k;
        int t = e / 73728, r = e % 73728;
        int kk = r / 8192; r %= 8192;
        int co = r / 64, ci = r % 64;
        w2s[e] = f2bf(W2[(size_t)(t * 128 + co) * 576 + ci * 9 + kk]);
    }
#pragma unroll
    for (int k = 0; k < 8; ++k) {               // W3s: (t,kk,co256,ci128)
        int e = gid * 8 + k;
        int t = e / 294912, r = e % 294912;
        int kk = r / 32768; r %= 32768;
        int co = r / 128, ci = r % 128;
        w3s[e] = f2bf(W3[(size_t)(t * 256 + co) * 1152 + ci * 9 + kk]);
    }
    if (gid < 55296) S3[gid] = 0.f;
    if (gid < 1152) {
        int t = gid / 384, r = gid % 384;
        if (r < 128) {
            const float* w = W2 + (size_t)(t * 128 + r) * 576; float s = 0.f;
            for (int k = 0; k < 576; ++k) { float v = bf2f(f2bf(w[k])); s += v * v; }
            wsq[192 + t * 128 + r] = s;
        } else {
            int c = r - 128;
            const float* w = W3 + (size_t)(t * 256 + c) * 1152; float s = 0.f;
            for (int k = 0; k < 1152; ++k) { float v = bf2f(f2bf(w[k])); s += v * v; }
            wsq[576 + t * 256 + c] = s;
        }
    }
}

// ------------------------- conv1: MFMA im2col, fused pool + S2 -------------
__global__ __launch_bounds__(576) void conv1_kernel(
        const float* __restrict__ x, const float* __restrict__ W1,
        const float* __restrict__ triw, const float* __restrict__ crb,
        const float* __restrict__ alp,
        unsigned short* __restrict__ p1u, float* __restrict__ S2) {
    __shared__ unsigned short simgbf[16 * 56];
    __shared__ unsigned short sA[576 * 40];
    __shared__ unsigned short sB[64 * 40];
    __shared__ float sxq[576];
    __shared__ float swq[64];

    int bi = blockIdx.x;
    int qv = blockIdx.y;
    int t = bi / 128, b = bi % 128;
    int tid = threadIdx.x;
    const float* xim = x + (size_t)(b * 3 + t) * 2304;
    int r0 = 12 * qv;

    for (int idx = tid; idx < 16 * 52; idx += 576) {
        int rl = idx / 52, cc = idx % 52;
        int y = r0 + rl - 2, xx = cc - 2;
        float v = (y >= 0 && y < 48 && xx >= 0 && xx < 48) ? xim[y * 48 + xx] : 0.f;
        simgbf[rl * 56 + cc] = f2bf(v);
    }
    if (tid < 64) {
        const float* wp = W1 + (size_t)t * 1600 + tid * 25;
        unsigned rw[20];
        float s = 0.f;
        unsigned short tmp[40];
#pragma unroll
        for (int k = 0; k < 25; ++k) {
            unsigned short u = f2bf(wp[k]);
            tmp[k] = u; float v = bf2f(u); s += v * v;
        }
#pragma unroll
        for (int k = 25; k < 40; ++k) tmp[k] = 0;
#pragma unroll
        for (int j = 0; j < 20; ++j) rw[j] = (unsigned)tmp[2 * j] | ((unsigned)tmp[2 * j + 1] << 16);
        uint4* bp = (uint4*)&sB[tid * 40];
#pragma unroll
        for (int j = 0; j < 5; ++j) {
            uint4 v4; v4.x = rw[4 * j]; v4.y = rw[4 * j + 1]; v4.z = rw[4 * j + 2]; v4.w = rw[4 * j + 3];
            bp[j] = v4;
        }
        swq[tid] = s;
    }
    __syncthreads();

    {
        int tile = tid >> 4, idx = tid & 15;
        int by = tile / 12, bx = tile % 12;
        int yy = idx >> 2, xx2 = idx & 3;
        int oy = by * 4 + yy, ox = bx * 4 + xx2;
        unsigned short row[40];
        float s = 0.f;
#pragma unroll
        for (int ky = 0; ky < 5; ++ky)
#pragma unroll
            for (int kx = 0; kx < 5; ++kx) {
                unsigned short u = simgbf[(oy + ky) * 56 + ox + kx];
                row[ky * 5 + kx] = u; float v = bf2f(u); s += v * v;
            }
#pragma unroll
        for (int k = 25; k < 40; ++k) row[k] = 0;
        unsigned rw[20];
#pragma unroll
        for (int j = 0; j < 20; ++j) rw[j] = (unsigned)row[2 * j] | ((unsigned)row[2 * j + 1] << 16);
        uint4* ap = (uint4*)&sA[tid * 40];
#pragma unroll
        for (int j = 0; j < 5; ++j) {
            uint4 v4; v4.x = rw[4 * j]; v4.y = rw[4 * j + 1]; v4.z = rw[4 * j + 2]; v4.w = rw[4 * j + 3];
            ap[j] = v4;
        }
        sxq[tid] = s;
    }
    __syncthreads();

    int w = tid >> 6, l = tid & 63;
    int lm = l & 15, q = l >> 4;

    f32x4 zz; zz[0] = 0.f; zz[1] = 0.f; zz[2] = 0.f; zz[3] = 0.f;
    f32x4 acc[4][4];
    bf16x8 aF[4], bF[4];
#pragma unroll
    for (int mt = 0; mt < 4; ++mt)
        aF[mt] = *(const bf16x8*)(&sA[((w * 4 + mt) * 16 + lm) * 40 + q * 8]);
#pragma unroll
    for (int nt = 0; nt < 4; ++nt)
        bF[nt] = *(const bf16x8*)(&sB[(nt * 16 + lm) * 40 + q * 8]);
#pragma unroll
    for (int mt = 0; mt < 4; ++mt)
#pragma unroll
        for (int nt = 0; nt < 4; ++nt)
            acc[mt][nt] = __builtin_amdgcn_mfma_f32_16x16x32_bf16(aF[mt], bF[nt], zz, 0, 0, 0);

    float wqv[4];
#pragma unroll
    for (int nt = 0; nt < 4; ++nt) wqv[nt] = swq[nt * 16 + lm];

    float tw = triw[t * 3 + 0], itw = 1.f / tw;
    float cb = crb[t * 3 + 0];
    float al = alp[t * 2 + 0];
    float apw[4] = {al * al * al * 0.25f, al * al * 0.25f, al * 0.25f, 0.25f};
    int qa = q & 1;
    size_t imgbase = (size_t)bi * 43264;

#pragma unroll
    for (int mt = 0; mt < 4; ++mt) {
        int tile = w * 4 + mt;
        int by = tile / 12, bx = tile % 12;
        f32x4 xq = *(const f32x4*)&sxq[tile * 16 + q * 4];
        float s2loc[2] = {0.f, 0.f};
        int py_g = qv * 6 + by * 2 + (q >> 1);
        int cell0 = (py_g + 1) * 26 + (bx * 2 + 1);
        float pv[4][2];
#pragma unroll
        for (int nt = 0; nt < 4; ++nt) {
            float hw[4];
#pragma unroll
            for (int r = 0; r < 4; ++r) {
                float d = fmaf(-2.f, acc[mt][nt][r], xq[r]) + wqv[nt];
                d = fminf(fmaxf(d, 0.f), tw);
                float h = 1.f - d * itw;
                h = (h >= cb) ? h : 0.f;
                hw[r] = h * apw[qa * 2 + (r & 1)];
            }
            float ph0 = hw[0] + hw[1], ph1 = hw[2] + hw[3];
            float p0 = ph0 + __shfl_xor(ph0, 16, 64);
            float p1 = ph1 + __shfl_xor(ph1, 16, 64);
            unsigned short u0 = f2bf(p0), u1 = f2bf(p1);
            float v0 = bf2f(u0), v1 = bf2f(u1);
            s2loc[0] += v0 * v0;
            s2loc[1] += v1 * v1;
            pv[nt][0] = p0; pv[nt][1] = p1;
        }
#pragma unroll
        for (int m2 = 1; m2 < 16; m2 <<= 1) {
            s2loc[0] += __shfl_xor(s2loc[0], m2, 64);
            s2loc[1] += __shfl_xor(s2loc[1], m2, 64);
        }
        if ((q & 1) == 0) {
#pragma unroll
            for (int nt = 0; nt < 4; ++nt) {
                p1u[imgbase + (size_t)cell0 * 64 + nt * 16 + lm] = f2bf(pv[nt][0]);
                p1u[imgbase + (size_t)(cell0 + 1) * 64 + nt * 16 + lm] = f2bf(pv[nt][1]);
            }
            if (lm == 0) {
                S2[(size_t)bi * 576 + py_g * 24 + bx * 2] = s2loc[0];
                S2[(size_t)bi * 576 + py_g * 24 + bx * 2 + 1] = s2loc[1];
            }
        }
    }

    if (tid < 200) {
        int e = qv * 200 + tid;
        int bc = e >> 3, c8 = e & 7;
        int cell;
        if (bc < 26) cell = bc;
        else if (bc < 52) cell = 650 + (bc - 26);
        else { int r = bc - 52; cell = (1 + (r >> 1)) * 26 + ((r & 1) * 25); }
        uint4 z; z.x = 0; z.y = 0; z.z = 0; z.w = 0;
        *(uint4*)(p1u + imgbase + (size_t)cell * 64 + c8 * 8) = z;
    }
}

// ------------------------- conv2: half-image MFMA, fused pool + S3 ---------
// grid (768 = 384img x 2 halves, 2 co-halves), block 576 = 9 waves.
// M=288 (18 tiles of 4x4 conv points), N=64, K = 2ks x 9kk x 32ci.
// LDS: img [0,27648) 1728x16B swizzled; w [27648,64512) 2304x16B swizzled;
//      sS 64512 (364 f), sxqm 65968 (288 f), swq 67120 (64 f). total 67376 B.
__global__ __launch_bounds__(576, 5) void conv2_kernel(
        const unsigned short* __restrict__ p1u, const unsigned short* __restrict__ w2s,
        const float* __restrict__ S2, const float* __restrict__ triw,
        const float* __restrict__ crb, const float* __restrict__ alp,
        const float* __restrict__ wsq, unsigned short* __restrict__ p2u,
        float* __restrict__ S3) {
    extern __shared__ char sm[];
    float* sS   = (float*)(sm + 64512);
    float* sxqm = (float*)(sm + 65968);
    float* swq  = (float*)(sm + 67120);

    int ih = blockIdx.x;
    int i = ih >> 1, h = ih & 1;
    int t = i / 128;
    int co0 = blockIdx.y * 64;
    int tid = threadIdx.x;
    int w = tid >> 6, l = tid & 63;
    int lm = l & 15, q = l >> 4;

    for (int e = tid; e < 364; e += 576) {
        int rl = e / 26, cc = e % 26;
        int gy = 12 * h + rl - 1, gx = cc - 1;
        sS[e] = (gy >= 0 && gy < 24 && gx >= 0 && gx < 24)
                    ? S2[(size_t)i * 576 + gy * 24 + gx] : 0.f;
    }
    if (tid < 64) swq[tid] = wsq[192 + t * 128 + co0 + tid];
    __syncthreads();
    if (tid < 288) {
        int tile = tid >> 4, idx = tid & 15;
        int by = tile / 6, bx = tile % 6;
        int oy = by * 4 + (idx >> 2), ox = bx * 4 + (idx & 3);
        float s = 0.f;
#pragma unroll
        for (int ky = 0; ky < 3; ++ky)
#pragma unroll
            for (int kx = 0; kx < 3; ++kx) s += sS[(oy + ky) * 26 + ox + kx];
        sxqm[tid] = s;
    }

    int posA[2];
#pragma unroll
    for (int mt = 0; mt < 2; ++mt) {
        int tile = w * 2 + mt;
        int by = tile / 6, bx = tile % 6;
        posA[mt] = (by * 4 + (lm >> 2)) * 26 + bx * 4 + (lm & 3);
    }

    f32x4 zz; zz[0] = 0.f; zz[1] = 0.f; zz[2] = 0.f; zz[3] = 0.f;
    f32x4 acc[2][4];
#pragma unroll
    for (int a = 0; a < 2; ++a)
#pragma unroll
        for (int bb = 0; bb < 4; ++bb) acc[a][bb] = zz;

    for (int ks = 0; ks < 2; ++ks) {
        __syncthreads();
        // img: 364 cells x 4 chunks (32ci half), swizzled
#pragma unroll
        for (int it = 0; it < 3; ++it) {
            int L = it * 576 + tid;
            int Lc = (L < 1456) ? L : 0;
            int cell = Lc >> 2, pos = Lc & 3;
            const unsigned short* g = p1u + ((size_t)i * 676 + cell + h * 312) * 64
                                      + ks * 32 + (((pos - cell) & 3) << 3);
            async16(sm + ((L & ~63) << 4), g);
        }
        // weights: 9kk x 64co x 32ci = 2304 chunks
#pragma unroll
        for (int it = 0; it < 4; ++it) {
            int L = it * 576 + tid;
            int row = L >> 2, pos = L & 3;
            int kk = row >> 6, n = row & 63;
            const unsigned short* g = w2s + ((size_t)(t * 9 + kk) * 128 + co0 + n) * 64
                                      + ks * 32 + (((pos - row) & 3) << 3);
            async16(sm + 27648 + ((L & ~63) << 4), g);
        }
        __builtin_amdgcn_s_waitcnt(0);
        __syncthreads();
#pragma unroll
        for (int kk = 0; kk < 9; ++kk) {
            int kof = (kk / 3) * 26 + (kk % 3);
            bf16x8 aF2[2], bF2[4];
#pragma unroll
            for (int mt = 0; mt < 2; ++mt) {
                int ci = posA[mt] + kof;
                aF2[mt] = *(const bf16x8*)(sm + ci * 64 + ((q + ci) & 3) * 16);
            }
#pragma unroll
            for (int nt = 0; nt < 4; ++nt) {
                int r = kk * 64 + nt * 16 + lm;
                bF2[nt] = *(const bf16x8*)(sm + 27648 + r * 64 + ((q + r) & 3) * 16);
                acc[0][nt] = __builtin_amdgcn_mfma_f32_16x16x32_bf16(aF2[0], bF2[nt], acc[0][nt], 0, 0, 0);
                acc[1][nt] = __builtin_amdgcn_mfma_f32_16x16x32_bf16(aF2[1], bF2[nt], acc[1][nt], 0, 0, 0);
            }
        }
    }

    float tw = triw[t * 3 + 1], itw = 1.f / tw, cb = crb[t * 3 + 1], al = alp[t * 2 + 1];
    float apw[4] = {al * al * al * 0.25f, al * al * 0.25f, al * 0.25f, 0.25f};
    int qa = q & 1;

#pragma unroll
    for (int mt = 0; mt < 2; ++mt) {
        int tile = w * 2 + mt;
        int by = tile / 6, bx = tile % 6;
        f32x4 xq = *(const f32x4*)(sxqm + tile * 16 + q * 4);
        float s3loc[2] = {0.f, 0.f};
        unsigned short pu[4][2];
#pragma unroll
        for (int nt = 0; nt < 4; ++nt) {
            float wq = swq[nt * 16 + lm];
            float hw[4];
#pragma unroll
            for (int r = 0; r < 4; ++r) {
                float d = fmaf(-2.f, acc[mt][nt][r], xq[r]) + wq;
                d = fminf(fmaxf(d, 0.f), tw);
                float hv = 1.f - d * itw;
                hv = (hv >= cb) ? hv : 0.f;
                hw[r] = hv * apw[qa * 2 + (r & 1)];
            }
            float ph0 = hw[0] + hw[1], ph1 = hw[2] + hw[3];
            float p0 = ph0 + __shfl_xor(ph0, 16, 64);
            float p1 = ph1 + __shfl_xor(ph1, 16, 64);
            unsigned short u0 = f2bf(p0), u1 = f2bf(p1);
            float v0 = bf2f(u0), v1 = bf2f(u1);
            s3loc[0] += v0 * v0;
            s3loc[1] += v1 * v1;
            pu[nt][0] = u0; pu[nt][1] = u1;
        }
#pragma unroll
        for (int m2 = 1; m2 < 16; m2 <<= 1) {
            s3loc[0] += __shfl_xor(s3loc[0], m2, 64);
            s3loc[1] += __shfl_xor(s3loc[1], m2, 64);
        }
        if ((q & 1) == 0) {
            int py = h * 6 + by * 2 + (q >> 1);
            int px0 = bx * 2;
            int cell = (py + 1) * 14 + px0 + 1;
#pragma unroll
            for (int nt = 0; nt < 4; ++nt) {
                p2u[((size_t)i * 196 + cell) * 128 + co0 + nt * 16 + lm] = pu[nt][0];
                p2u[((size_t)i * 196 + cell + 1) * 128 + co0 + nt * 16 + lm] = pu[nt][1];
            }
            if (lm == 0) {
                atomicAdd(&S3[(size_t)i * 144 + py * 12 + px0], s3loc[0]);
                atomicAdd(&S3[(size_t)i * 144 + py * 12 + px0 + 1], s3loc[1]);
            }
        }
    }

    // border zeros: 52 cells/img split by half; this block covers its co-half
    if (tid < 208) {
        int bc_l = tid >> 3, c8 = tid & 7;
        int bc = h * 26 + bc_l;
        int cell;
        if (bc < 14) cell = bc;
        else if (bc < 28) cell = 182 + (bc - 14);
        else { int r = bc - 28; cell = (1 + (r >> 1)) * 14 + ((r & 1) * 13); }
        uint2 z; z.x = 0; z.y = 0;
        *(uint2*)(p2u + ((size_t)i * 196 + cell) * 128 + co0 + c8 * 8) = z;
        *(uint2*)(p2u + ((size_t)i * 196 + cell) * 128 + co0 + c8 * 8 + 4) = z;
    }
}

// ------------------------- conv3: 2-img MFMA GEMM -> h3 bf16 ---------------
// grid (192, 4), block 576 = 9 waves; M=288 (2 img x 144), N=64, K=4ks x 9kk x 32.
// LDS: img [0,27648) swizzled; w [27648,64512); sS3 64512 (392 f),
//      sxq3 66080 (288 f), wsqh3 67232 (64 f). total 67488 B.
__global__ __launch_bounds__(576, 5) void conv3_kernel(
        const unsigned short* __restrict__ p2u, const unsigned short* __restrict__ w3s,
        const float* __restrict__ S3, const float* __restrict__ triw,
        const float* __restrict__ crb, const float* __restrict__ wsq,
        unsigned short* __restrict__ h3bf) {
    extern __shared__ char sm[];
    float* sS3   = (float*)(sm + 64512);
    float* sxq3  = (float*)(sm + 66080);
    float* wsqh3 = (float*)(sm + 67232);

    int g = blockIdx.x;
    int i0 = g * 2;
    int t = i0 / 128;
    int co0 = blockIdx.y * 64;
    int tid = threadIdx.x;
    int w = tid >> 6, l = tid & 63;
    int lm = l & 15, q = l >> 4;

    for (int e = tid; e < 392; e += 576) {
        int il = e / 196, cl = e % 196;
        int yy = cl / 14, xx = cl % 14;
        sS3[e] = (yy >= 1 && yy <= 12 && xx >= 1 && xx <= 12)
                     ? S3[(size_t)(i0 + il) * 144 + (yy - 1) * 12 + (xx - 1)] : 0.f;
    }
    if (tid < 64) wsqh3[tid] = wsq[576 + t * 256 + co0 + tid];
    __syncthreads();
    if (tid < 288) {
        int il = tid / 144, s = tid % 144;
        int oy = s / 12, ox = s % 12;
        float sum = 0.f;
#pragma unroll
        for (int ky = 0; ky < 3; ++ky)
#pragma unroll
            for (int kx = 0; kx < 3; ++kx)
                sum += sS3[il * 196 + (oy + ky) * 14 + (ox + kx)];
        sxq3[tid] = sum;
    }

    int posA[2], img_l[2], s0a[2];
#pragma unroll
    for (int mt = 0; mt < 2; ++mt) {
        int tb = w * 32 + mt * 16;
        int il = tb / 144, s0 = tb % 144;
        int s = s0 + lm;
        posA[mt] = il * 196 + (s / 12) * 14 + (s % 12);
        img_l[mt] = il; s0a[mt] = s0;
    }

    f32x4 zz; zz[0] = 0.f; zz[1] = 0.f; zz[2] = 0.f; zz[3] = 0.f;
    f32x4 acc[2][4];
#pragma unroll
    for (int a = 0; a < 2; ++a)
#pragma unroll
        for (int bb = 0; bb < 4; ++bb) acc[a][bb] = zz;

    for (int ks = 0; ks < 4; ++ks) {
        __syncthreads();
        // img: 392 cells x 4 chunks = 1568
#pragma unroll
        for (int it = 0; it < 3; ++it) {
            int L = it * 576 + tid;
            int Lc = (L < 1568) ? L : 0;
            int cell = Lc >> 2, pos = Lc & 3;
            int il = cell / 196, cl = cell - il * 196;
            const unsigned short* gp = p2u + ((size_t)(i0 + il) * 196 + cl) * 128
                                       + ks * 32 + (((pos - cell) & 3) << 3);
            async16(sm + ((L & ~63) << 4), gp);
        }
        // weights: 9kk x 64co x 32ci = 2304 chunks
#pragma unroll
        for (int it = 0; it < 4; ++it) {
            int L = it * 576 + tid;
            int row = L >> 2, pos = L & 3;
            int kk = row >> 6, n = row & 63;
            const unsigned short* gp = w3s + ((size_t)(t * 9 + kk) * 256 + co0 + n) * 128
                                       + ks * 32 + (((pos - row) & 3) << 3);
            async16(sm + 27648 + ((L & ~63) << 4), gp);
        }
        __builtin_amdgcn_s_waitcnt(0);
        __syncthreads();
#pragma unroll
        for (int kk = 0; kk < 9; ++kk) {
            int kof = (kk / 3) * 14 + (kk % 3);
            bf16x8 aF3[2], bF3[4];
#pragma unroll
            for (int mt = 0; mt < 2; ++mt) {
                int ci = posA[mt] + kof;
                aF3[mt] = *(const bf16x8*)(sm + ci * 64 + ((q + ci) & 3) * 16);
            }
#pragma unroll
            for (int nt = 0; nt < 4; ++nt) {
                int r = kk * 64 + nt * 16 + lm;
                bF3[nt] = *(const bf16x8*)(sm + 27648 + r * 64 + ((q + r) & 3) * 16);
                acc[0][nt] = __builtin_amdgcn_mfma_f32_16x16x32_bf16(aF3[0], bF3[nt], acc[0][nt], 0, 0, 0);
                acc[1][nt] = __builtin_amdgcn_mfma_f32_16x16x32_bf16(aF3[1], bF3[nt], acc[1][nt], 0, 0, 0);
            }
        }
    }
    __syncthreads();   // img region dead -> per-wave transpose tiles

    float tw = triw[t * 3 + 2], itw = 1.f / tw, cb = crb[t * 3 + 2];
    float* tile = (float*)(sm + w * 1280);   // 16x20 floats, wave-private
#pragma unroll
    for (int mt = 0; mt < 2; ++mt) {
        int il = img_l[mt], s0 = s0a[mt];
        int bidx = (i0 + il) - t * 128;
        unsigned short* gbase = h3bf + (size_t)bidx * 110592 + (size_t)t * 36864;
#pragma unroll
        for (int nt = 0; nt < 4; ++nt) {
            float wq = wsqh3[nt * 16 + lm];
#pragma unroll
            for (int r = 0; r < 4; ++r) {
                float d = sxq3[il * 144 + s0 + q * 4 + r] - 2.f * acc[mt][nt][r] + wq;
                d = fminf(fmaxf(d, 0.f), tw);
                float hv = 1.f - d * itw;
                hv = (hv >= cb) ? hv : 0.f;
                tile[lm * 20 + q * 4 + r] = hv;
            }
            f32x4 v = *(const f32x4*)(tile + (l >> 2) * 20 + (l & 3) * 4);
            uint2 uv; uv.x = pkbf(v[0], v[1]); uv.y = pkbf(v[2], v[3]);
            *(uint2*)(gbase + (size_t)(co0 + nt * 16 + (l >> 2)) * 144 + s0 + (l & 3) * 4) = uv;
        }
    }
}

// ------------------------- FC: LDS-free bf16 MFMA K-split ------------------
__global__ __launch_bounds__(512) void fc_kernel(
        const unsigned short* __restrict__ h3bf, const float* __restrict__ fcw,
        float* __restrict__ part) {
    int kb = blockIdx.x;
    int f0 = kb * 256;
    int tid = threadIdx.x;
    int w = tid >> 6, l = tid & 63;
    int lm = l & 15, q = l >> 4;

    const unsigned short* abase = h3bf + (size_t)(w * 16 + lm) * 110592 + f0 + q * 8;
    const float* brow[7];
#pragma unroll
    for (int nt = 0; nt < 7; ++nt) {
        int n = nt * 16 + lm;
        if (n > 99) n = 99;
        brow[nt] = fcw + (size_t)n * 110592 + f0 + q * 8;
    }

    f32x4 zz; zz[0] = 0.f; zz[1] = 0.f; zz[2] = 0.f; zz[3] = 0.f;
    f32x4 acc[7];
#pragma unroll
    for (int nt = 0; nt < 7; ++nt) acc[nt] = zz;

#pragma unroll 2
    for (int kc = 0; kc < 8; ++kc) {
        bf16x8 aF = *(const bf16x8*)(abase + kc * 32);
#pragma unroll
        for (int nt = 0; nt < 7; ++nt) {
            f32x4 b0 = *(const f32x4*)(brow[nt] + kc * 32);
            f32x4 b1 = *(const f32x4*)(brow[nt] + kc * 32 + 4);
            union { bf16x8 v; unsigned u[4]; } bF;
            bF.u[0] = pkbf(b0[0], b0[1]);
            bF.u[1] = pkbf(b0[2], b0[3]);
            bF.u[2] = pkbf(b1[0], b1[1]);
            bF.u[3] = pkbf(b1[2], b1[3]);
            acc[nt] = __builtin_amdgcn_mfma_f32_16x16x32_bf16(aF, bF.v, acc[nt], 0, 0, 0);
        }
    }

    float* pb = part + (size_t)kb * 14336;
#pragma unroll
    for (int nt = 0; nt < 7; ++nt)
#pragma unroll
        for (int r = 0; r < 4; ++r)
            pb[(w * 16 + q * 4 + r) * 112 + nt * 16 + lm] = acc[nt][r];
}

__global__ __launch_bounds__(256) void fc_red1_kernel(const float* __restrict__ part,
                                                      float* __restrict__ part2) {
    int c = blockIdx.x;
    int gid = blockIdx.y * 256 + threadIdx.x;
    if (gid >= 12800) return;
    const float* p = part + (size_t)(c * 54) * 14336 + (gid / 100) * 112 + gid % 100;
    float s = 0.f;
#pragma unroll 6
    for (int kb = 0; kb < 54; ++kb) s += p[(size_t)kb * 14336];
    part2[c * 12800 + gid] = s;
}

__global__ __launch_bounds__(256) void fc_red2_kernel(const float* __restrict__ part2,
                                                      const float* __restrict__ fcb,
                                                      float* __restrict__ out) {
    int gid = blockIdx.x * 256 + threadIdx.x;
    if (gid >= 12800) return;
    float s = fcb[gid % 100];
#pragma unroll
    for (int c = 0; c < 8; ++c) s += part2[c * 12800 + gid];
    out[gid] = s;
}

// ---------------------------------------------------------------------------
extern "C" void kernel_launch(void* const* d_in, const int* in_sizes, int n_in,
                              void* d_out, int out_size, void* d_ws, size_t ws_size,
                              hipStream_t stream) {
    const float* x    = (const float*)d_in[0];
    const float* W1   = (const float*)d_in[1];
    const float* W2   = (const float*)d_in[2];
    const float* W3   = (const float*)d_in[3];
    const float* triw = (const float*)d_in[4];
    const float* crb  = (const float*)d_in[5];
    const float* alp  = (const float*)d_in[6];
    const float* fcw  = (const float*)d_in[7];
    const float* fcb  = (const float*)d_in[8];
    float* out = (float*)d_out;
    float* ws  = (float*)d_ws;

    unsigned short* p1u = (unsigned short*)ws;
    unsigned short* p2u = (unsigned short*)(ws + OFF_P2CL);
    float* S2  = ws + OFF_S2;
    float* S3  = ws + OFF_S3;
    float* wsq = ws + OFF_WSQ;
    unsigned short* w2s = (unsigned short*)(ws + OFF_W2S);
    unsigned short* w3s = (unsigned short*)(ws + OFF_W3S);
    float* part  = ws + OFF_PART;
    float* part2 = ws + OFF_PART2;
    unsigned short* h3bf = (unsigned short*)ws;      // aliases p1u (dead by conv3)

    hipFuncSetAttribute((const void*)conv2_kernel,
                        hipFuncAttributeMaxDynamicSharedMemorySize, 67376);
    hipFuncSetAttribute((const void*)conv3_kernel,
                        hipFuncAttributeMaxDynamicSharedMemorySize, 67488);

    prep_kernel<<<dim3(432), dim3(256), 0, stream>>>(W2, W3, w2s, w3s, wsq, S3);
    conv1_kernel<<<dim3(384, 4), dim3(576), 0, stream>>>(x, W1, triw, crb, alp, p1u, S2);
    conv2_kernel<<<dim3(768, 2), dim3(576), 67376, stream>>>(p1u, w2s, S2, triw, crb, alp, wsq, p2u, S3);
    conv3_kernel<<<dim3(192, 4), dim3(576), 67488, stream>>>(p2u, w3s, S3, triw, crb, wsq, h3bf);
    fc_kernel<<<dim3(432), dim3(512), 0, stream>>>(h3bf, fcw, part);
    fc_red1_kernel<<<dim3(8, 50), dim3(256), 0, stream>>>(part, part2);
    fc_red2_kernel<<<dim3(50), dim3(256), 0, stream>>>(part2, fcb, out);
}